// Round 7
// baseline (437.330 us; speedup 1.0000x reference)
//
#include <hip/hip_runtime.h>
#include <hip/hip_bf16.h>

// ---------------- types ----------------
using short8 = __attribute__((ext_vector_type(8))) short;   // 8 bf16 (4 VGPRs)
using f32x4  = __attribute__((ext_vector_type(4))) float;   // 4 fp32 acc

#define LSK 72   // LDS row stride (shorts) for Ps tile

#define GLDS(gptr, lptr) __builtin_amdgcn_global_load_lds( \
    (const __attribute__((address_space(1))) void*)(gptr), \
    (__attribute__((address_space(3))) void*)(lptr), 16, 0, 0)

#define GLDS4(gptr, lptr) __builtin_amdgcn_global_load_lds( \
    (const __attribute__((address_space(1))) void*)(gptr), \
    (__attribute__((address_space(3))) void*)(lptr), 4, 0, 0)

// top-of-iter sync: drain PREVIOUS tile's loads (keep the N just-issued in flight),
// then barrier; sched_barrier pins compute below the barrier (rule 18).
#define TOPSYNC_V(n_lit) do { \
    asm volatile("s_waitcnt vmcnt(" #n_lit ")" ::: "memory"); \
    __builtin_amdgcn_s_barrier(); \
    __builtin_amdgcn_sched_barrier(0); \
} while (0)
// end-of-iter sync: all LDS reads of cur done before anyone overwrites it next iter.
#define ENDSYNC() do { \
    __builtin_amdgcn_sched_barrier(0); \
    __builtin_amdgcn_s_barrier(); \
} while (0)

static __device__ __forceinline__ short f2b(float f) {
    unsigned u = __builtin_bit_cast(unsigned, f);
    unsigned r = (u + 0x7fffu + ((u >> 16) & 1u)) >> 16;
    return (short)r;
}

// ---------------- convert kernels ----------------
__global__ void cvt_bf16(const float* __restrict__ in, short* __restrict__ out, int n) {
    int i = (blockIdx.x * 256 + threadIdx.x) * 4;
    if (i >= n) return;
    float4 v = *(const float4*)(in + i);
    short4 o = make_short4(f2b(v.x), f2b(v.y), f2b(v.z), f2b(v.w));
    *(short4*)(out + i) = o;
}

// 4 weights f32 [1024][1024] -> Wt bf16 [N][K], dsts contiguous from Wt0
__global__ void cvt_t4(const float* __restrict__ W0, const float* __restrict__ W1,
                       const float* __restrict__ W2, const float* __restrict__ W3,
                       short* __restrict__ Wt0) {
    __shared__ short tile[32][33];
    const float* Ws[4] = {W0, W1, W2, W3};
    const float* W = Ws[blockIdx.z];
    short* Wt = Wt0 + (size_t)blockIdx.z * 1024 * 1024;
    const int K = 1024, N = 1024;
    int n0 = blockIdx.x * 32, k0 = blockIdx.y * 32;
    int tx = threadIdx.x, ty = threadIdx.y; // (32,8)
#pragma unroll
    for (int i = 0; i < 4; i++) {
        int r = ty + i * 8;
        tile[r][tx] = f2b(W[(size_t)(k0 + r) * N + n0 + tx]);
    }
    __syncthreads();
#pragma unroll
    for (int i = 0; i < 4; i++) {
        int r = ty + i * 8;
        Wt[(size_t)(n0 + r) * K + k0 + tx] = tile[tx][r];
    }
}

// ---------------- GEMM 256x256: 8-wave, counted-vmcnt deep pipeline ----------------
// KV projection only (M=16384, N=2048, K=1024).
// Per K-tile: {STAGE all 8 glds of next tile; vmcnt(8) -> drains PREV tile (full-iter
// cover); barrier; 64 MFMA (no inner barriers; waves only read LDS); barrier}.
// n<1024 -> K bf16 [m][1024]; n>=1024 -> Vt [b][h][d][s].
__global__ __launch_bounds__(512, 1) void gemm256(
    const short* __restrict__ A, const short* __restrict__ Bt,
    short* __restrict__ CK, short* __restrict__ CVt)
{
    __shared__ short As[2][256 * 64];
    __shared__ short Bs[2][256 * 64];
    const int tid = threadIdx.x;
    const int w = tid >> 6, L = tid & 63, quad = L >> 4, l16 = L & 15;
    const int wr = w >> 2, wcn = w & 3;   // 2x4 wave grid; per-wave output 128x64

    const int lin = blockIdx.y * gridDim.x + blockIdx.x;
    const int xcd = lin & 7, idx = lin >> 3;
    const int mPer = gridDim.y >> 3;      // 64/8 = 8
    const int my = xcd * mPer + idx / gridDim.x;
    const int nx = idx % gridDim.x;
    const int n0 = nx * 256, m0 = my * 256;

    const int K = 1024;
    const int srow_in = L >> 3;                    // 0..7 within 8-row chunk
    const int sgcol   = ((L & 7) ^ srow_in) * 8;   // pre-swizzled global col (shorts)

    // 64 chunks of 8 rows x 64 cols: waves 0-3 stage A (chunks 0-31), 4-7 stage B.
    auto STAGE_ALL = [&](int buf, int kt) {
        const int k0 = kt * 64;
#pragma unroll
        for (int j = 0; j < 8; j++) {
            int c = w * 8 + j;
            if (c < 32) {
                int row = c * 8 + srow_in;
                GLDS(A + (size_t)(m0 + row) * K + k0 + sgcol, &As[buf][c * 512]);
            } else {
                int row = (c - 32) * 8 + srow_in;
                GLDS(Bt + (size_t)(n0 + row) * K + k0 + sgcol, &Bs[buf][(c - 32) * 512]);
            }
        }
    };

    f32x4 acc[2][4][4];
#pragma unroll
    for (int mh = 0; mh < 2; mh++)
#pragma unroll
        for (int mi = 0; mi < 4; mi++)
#pragma unroll
            for (int ni = 0; ni < 4; ni++) acc[mh][mi][ni] = (f32x4){0.f, 0.f, 0.f, 0.f};

    STAGE_ALL(0, 0);   // prologue; drained by first TOPSYNC

    for (int t = 0; t < 16; t++) {
        const int cur = t & 1;
        if (t < 15) {
            STAGE_ALL(cur ^ 1, t + 1);
            TOPSYNC_V(8);          // drain prev tile's 8, keep the 8 just issued flying
        } else {
            TOPSYNC_V(0);          // last tile: drain fully
        }
#pragma unroll
        for (int ks = 0; ks < 2; ks++) {
            // col-group for k-slice ks*32 is (ks*4 + quad); round-6 bug was (ks + quad)
            const int swz = (((ks * 4) + quad) ^ (l16 & 7)) << 3;
            short8 bf[4];
#pragma unroll
            for (int ni = 0; ni < 4; ni++)
                bf[ni] = *(const short8*)&Bs[cur][(wcn * 64 + ni * 16 + l16) * 64 + swz];
#pragma unroll
            for (int mh = 0; mh < 2; mh++) {
                short8 af[4];
#pragma unroll
                for (int mi = 0; mi < 4; mi++)
                    af[mi] = *(const short8*)&As[cur][(wr * 128 + mh * 64 + mi * 16 + l16) * 64 + swz];
                __builtin_amdgcn_s_setprio(1);
#pragma unroll
                for (int mi = 0; mi < 4; mi++)
#pragma unroll
                    for (int ni = 0; ni < 4; ni++)
                        acc[mh][mi][ni] = __builtin_amdgcn_mfma_f32_16x16x32_bf16(af[mi], bf[ni], acc[mh][mi][ni], 0, 0, 0);
                __builtin_amdgcn_s_setprio(0);
            }
        }
        ENDSYNC();   // all reads of buf[cur] done; next iter may overwrite it
    }

    // epilogue: dual KV write
#pragma unroll
    for (int mh = 0; mh < 2; mh++)
#pragma unroll
        for (int ni = 0; ni < 4; ni++) {
            int n = n0 + wcn * 64 + ni * 16 + l16;
#pragma unroll
            for (int mi = 0; mi < 4; mi++)
#pragma unroll
                for (int r = 0; r < 4; r++) {
                    int m = m0 + wr * 128 + mh * 64 + mi * 16 + quad * 4 + r;
                    float v = acc[mh][mi][ni][r];
                    if (n < 1024) CK[(size_t)m * 1024 + n] = f2b(v);
                    else {
                        int h = (n - 1024) >> 6, d = n & 63;
                        int b = m >> 11, s = m & 2047;
                        CVt[(((size_t)b * 16 + h) * 64 + d) * 2048 + s] = f2b(v);
                    }
                }
        }
}

// ---------------- GEMM: 128m x 128n tile, BK=64, counted-vmcnt 2-phase ----------------
// Q/O projections. mode 0: bf16 [m][n]; mode 1: f32 [m][n]
__global__ __launch_bounds__(256) void gemm128(
    const short* __restrict__ A, const short* __restrict__ Bt,
    const float* __restrict__ bias, void* __restrict__ Cout,
    int M, int mode)
{
    __shared__ short As[2][128 * 64];
    __shared__ short Bs[2][128 * 64];
    const int tid = threadIdx.x;
    const int w = tid >> 6, L = tid & 63, quad = L >> 4, l16 = L & 15;
    const int wr = w >> 1, wc = w & 1;   // 2x2 wave grid, each wave owns 64x64

    const int lin = blockIdx.y * gridDim.x + blockIdx.x;
    const int xcd = lin & 7, idx = lin >> 3;
    const int mPer = gridDim.y >> 3;
    const int my = xcd * mPer + idx / gridDim.x;
    const int nx = idx % gridDim.x;
    const int n0 = nx * 128, m0 = my * 128;

    const int K = 1024;
    const int srow_in = L >> 3;                        // 0..7 within chunk
    const int sgcol   = ((L & 7) ^ (srow_in & 7)) * 8; // swizzled global col (shorts)

    auto STAGE = [&](int buf, int k0) {
#pragma unroll
        for (int j = 0; j < 8; j++) {
            int c = w * 8 + j;
            if (c < 16) {
                int row = c * 8 + srow_in;
                GLDS(A + (size_t)(m0 + row) * K + k0 + sgcol, &As[buf][c * 512]);
            } else {
                int row = (c - 16) * 8 + srow_in;
                GLDS(Bt + (size_t)(n0 + row) * K + k0 + sgcol, &Bs[buf][(c - 16) * 512]);
            }
        }
    };

    f32x4 acc[4][4];
#pragma unroll
    for (int mi = 0; mi < 4; mi++)
#pragma unroll
        for (int ni = 0; ni < 4; ni++) acc[mi][ni] = (f32x4){0.f, 0.f, 0.f, 0.f};

    STAGE(0, 0);   // prologue

    for (int t = 0; t < 16; t++) {
        const int cur = t & 1;
        if (t < 15) {
            STAGE(cur ^ 1, (t + 1) * 64);
            TOPSYNC_V(8);
        } else {
            TOPSYNC_V(0);
        }
#pragma unroll
        for (int kk = 0; kk < 64; kk += 32) {
            const int swz = (((kk >> 3) + quad) ^ (l16 & 7)) << 3;
            short8 af[4], bf[4];
#pragma unroll
            for (int mi = 0; mi < 4; mi++)
                af[mi] = *(const short8*)&As[cur][(wr * 64 + mi * 16 + l16) * 64 + swz];
#pragma unroll
            for (int ni = 0; ni < 4; ni++)
                bf[ni] = *(const short8*)&Bs[cur][(wc * 64 + ni * 16 + l16) * 64 + swz];
#pragma unroll
            for (int mi = 0; mi < 4; mi++)
#pragma unroll
                for (int ni = 0; ni < 4; ni++)
                    acc[mi][ni] = __builtin_amdgcn_mfma_f32_16x16x32_bf16(af[mi], bf[ni], acc[mi][ni], 0, 0, 0);
        }
        ENDSYNC();
    }

#pragma unroll
    for (int ni = 0; ni < 4; ni++) {
        int n = n0 + wc * 64 + ni * 16 + l16;
        float bv = bias ? bias[n] : 0.f;
#pragma unroll
        for (int mi = 0; mi < 4; mi++) {
#pragma unroll
            for (int r = 0; r < 4; r++) {
                int m = m0 + wr * 64 + mi * 16 + quad * 4 + r;
                float v = acc[mi][ni][r] + bv;
                if (mode == 1)      ((float*)Cout)[(size_t)m * 1024 + n] = v;
                else                ((short*)Cout)[(size_t)m * 1024 + n] = f2b(v);
            }
        }
    }
}

// ---------------- flash attention: t-tile=128, s-tile=128, counted-vmcnt dbuf ----------------
__global__ __launch_bounds__(512) void attn_flash(
    const short* __restrict__ Qb, const short* __restrict__ Kb, const short* __restrict__ Vtb,
    const int* __restrict__ mask, short* __restrict__ Cb, float* __restrict__ lse)
{
    __shared__ short Qs[128 * 64];
    __shared__ short Ks[2][128 * 64];      // dbuf K rows
    __shared__ short Vts[2][128 * 64];     // dbuf, two [64 d][64 s] halves each
    __shared__ short Ps[128 * LSK];
    __shared__ int   negi[2048];           // whole-row mask, staged once in prologue
    const int tid = threadIdx.x;
    const int w = tid >> 6, L = tid & 63, quad = L >> 4, l16 = L & 15;
    const int t0 = blockIdx.x * 128, h = blockIdx.y, b = blockIdx.z;
    const int S = 2048, T = 512, H = 1024;
    const int trow = w * 16;
    const int srow = L >> 3;
    const int sg   = ((L & 7) ^ srow) * 8;

    auto STAGE_KV = [&](int buf, int s0) {   // 4 glds/thread, uniform across waves
#pragma unroll
        for (int j = 0; j < 2; j++) {
            int krow = w * 16 + j * 8 + srow;
            GLDS(Kb + ((size_t)b * S + s0 + krow) * H + h * 64 + sg, &Ks[buf][(w * 16 + j * 8) * 64]);
            int c = w * 2 + j, hf = c >> 3, d0 = (c & 7) * 8;
            GLDS(Vtb + (((size_t)b * 16 + h) * 64 + d0 + srow) * S + s0 + hf * 64 + sg, &Vts[buf][c * 512]);
        }
    };

    // prologue: Q tile + whole mask row + first K/V tile; full drain once
#pragma unroll
    for (int j = 0; j < 2; j++) {
        int row = w * 16 + j * 8 + srow;
        GLDS(Qb + ((size_t)b * T + t0 + row) * H + h * 64 + sg, &Qs[(w * 16 + j * 8) * 64]);
    }
#pragma unroll
    for (int r = 0; r < 4; r++)
        GLDS4(mask + (size_t)b * S + r * 512 + w * 64 + L, &negi[r * 512 + w * 64]);
    STAGE_KV(0, 0);
    __syncthreads();

    short8 aq[2];
#pragma unroll
    for (int kk = 0; kk < 2; kk++)
        aq[kk] = *(const short8*)&Qs[(trow + l16) * 64 + ((kk * 4 + quad) ^ (l16 & 7)) * 8];

    f32x4 Oacc[4];
#pragma unroll
    for (int nt = 0; nt < 4; nt++) Oacc[nt] = (f32x4){0.f, 0.f, 0.f, 0.f};
    float lsum[4] = {0.f, 0.f, 0.f, 0.f};

    for (int it = 0; it < 16; it++) {
        const int cur = it & 1;
        if (it < 15) {
            STAGE_KV(cur ^ 1, (it + 1) * 128);
            TOPSYNC_V(4);
        } else {
            TOPSYNC_V(0);
        }
#pragma unroll
        for (int hf = 0; hf < 2; hf++) {
            // S = Q K^T for this 64-s half
            f32x4 sacc[4];
#pragma unroll
            for (int nt = 0; nt < 4; nt++) sacc[nt] = (f32x4){0.f, 0.f, 0.f, 0.f};
#pragma unroll
            for (int kk = 0; kk < 2; kk++) {
#pragma unroll
                for (int nt = 0; nt < 4; nt++) {
                    short8 bf = *(const short8*)&Ks[cur][(hf * 64 + nt * 16 + l16) * 64 + ((kk * 4 + quad) ^ (l16 & 7)) * 8];
                    sacc[nt] = __builtin_amdgcn_mfma_f32_16x16x32_bf16(aq[kk], bf, sacc[nt], 0, 0, 0);
                }
            }
            // p = exp(s/8 + neg); write Ps (wave-private rows)
#pragma unroll
            for (int nt = 0; nt < 4; nt++) {
                float ng = negi[it * 128 + hf * 64 + nt * 16 + l16] ? 0.f : -1e20f;
#pragma unroll
                for (int r = 0; r < 4; r++) {
                    float e = __expf(fmaf(sacc[nt][r], 0.125f, ng));
                    lsum[r] += e;
                    Ps[(trow + quad * 4 + r) * LSK + nt * 16 + l16] = f2b(e);
                }
            }
            // O += P V
#pragma unroll
            for (int kk = 0; kk < 2; kk++) {
                short8 af = *(const short8*)&Ps[(trow + l16) * LSK + kk * 32 + quad * 8];
#pragma unroll
                for (int nt = 0; nt < 4; nt++) {
                    short8 bf = *(const short8*)&Vts[cur][hf * 4096 + (nt * 16 + l16) * 64 + ((kk * 4 + quad) ^ (l16 & 7)) * 8];
                    Oacc[nt] = __builtin_amdgcn_mfma_f32_16x16x32_bf16(af, bf, Oacc[nt], 0, 0, 0);
                }
            }
        }
        ENDSYNC();
    }
    // rowsum reduce across the 16 lanes of each quad-group
#pragma unroll
    for (int r = 0; r < 4; r++) {
#pragma unroll
        for (int off = 1; off < 16; off <<= 1)
            lsum[r] += __shfl_xor(lsum[r], off, 64);
    }
#pragma unroll
    for (int r = 0; r < 4; r++) {
        float inv = 1.0f / lsum[r];
        int t = t0 + trow + quad * 4 + r;
#pragma unroll
        for (int nt = 0; nt < 4; nt++) {
            int d = nt * 16 + l16;
            Cb[((size_t)b * T + t) * H + h * 64 + d] = f2b(Oacc[nt][r] * inv);
        }
        if (l16 == 0)
            lse[((size_t)b * 16 + h) * T + t] = __logf(lsum[r]);
    }
}

// ---------------- a_mean: out[b][t][s] = mean_h exp(qk/8 + neg - lse_h) ----------------
__global__ __launch_bounds__(256) void attn_amean(
    const short* __restrict__ Qb, const short* __restrict__ Kb,
    const int* __restrict__ mask, const float* __restrict__ lse, float* __restrict__ outA)
{
    __shared__ short Qs[2][64 * 64];
    __shared__ short Ks[2][64 * 64];
    __shared__ float neg[64];
    __shared__ float lss[16 * 64];
    const int tid = threadIdx.x;
    const int w = tid >> 6, L = tid & 63, quad = L >> 4, l16 = L & 15;
    const int s0 = blockIdx.x * 64, t0 = blockIdx.y * 64, b = blockIdx.z;
    const int S = 2048, T = 512, H = 1024;
    const int srow = L >> 3;
    const int sg   = ((L & 7) ^ srow) * 8;

    auto STAGE_QK = [&](int buf, int h) {   // 4 glds/thread, uniform
#pragma unroll
        for (int j = 0; j < 2; j++) {
            int row = w * 16 + j * 8 + srow;
            GLDS(Qb + ((size_t)b * T + t0 + row) * H + h * 64 + sg, &Qs[buf][(w * 16 + j * 8) * 64]);
            GLDS(Kb + ((size_t)b * S + s0 + row) * H + h * 64 + sg, &Ks[buf][(w * 16 + j * 8) * 64]);
        }
    };

    if (tid < 64) neg[tid] = mask[(size_t)b * S + s0 + tid] ? 0.f : -1e20f;
    for (int i = tid; i < 16 * 64; i += 256) {
        int hh = i >> 6, tt = i & 63;
        lss[i] = lse[((size_t)b * 16 + hh) * T + t0 + tt];
    }
    STAGE_QK(0, 0);
    __syncthreads();   // neg/lss settled, head-0 staged, vmcnt drained

    float am[4][4] = {};
    for (int h = 0; h < 16; h++) {
        const int cur = h & 1;
        if (h < 15) {
            STAGE_QK(cur ^ 1, h + 1);
            TOPSYNC_V(4);
        } else {
            TOPSYNC_V(0);
        }
        short8 aq[2];
#pragma unroll
        for (int kk = 0; kk < 2; kk++)
            aq[kk] = *(const short8*)&Qs[cur][(w * 16 + l16) * 64 + ((kk * 4 + quad) ^ (l16 & 7)) * 8];
        f32x4 sacc[4];
#pragma unroll
        for (int nt = 0; nt < 4; nt++) sacc[nt] = (f32x4){0.f, 0.f, 0.f, 0.f};
#pragma unroll
        for (int kk = 0; kk < 2; kk++) {
#pragma unroll
            for (int nt = 0; nt < 4; nt++) {
                short8 bf = *(const short8*)&Ks[cur][(nt * 16 + l16) * 64 + ((kk * 4 + quad) ^ (l16 & 7)) * 8];
                sacc[nt] = __builtin_amdgcn_mfma_f32_16x16x32_bf16(aq[kk], bf, sacc[nt], 0, 0, 0);
            }
        }
#pragma unroll
        for (int nt = 0; nt < 4; nt++) {
            float ng = neg[nt * 16 + l16];
#pragma unroll
            for (int r = 0; r < 4; r++) {
                int trow = w * 16 + quad * 4 + r;
                am[nt][r] += __expf(fmaf(sacc[nt][r], 0.125f, ng - lss[h * 64 + trow]));
            }
        }
        ENDSYNC();
    }
#pragma unroll
    for (int r = 0; r < 4; r++) {
        int t = t0 + w * 16 + quad * 4 + r;
#pragma unroll
        for (int nt = 0; nt < 4; nt++) {
            int s = s0 + nt * 16 + l16;
            outA[((size_t)b * T + t) * S + s] = am[nt][r] * 0.0625f;
        }
    }
}

// ---------------- launch ----------------
extern "C" void kernel_launch(void* const* d_in, const int* in_sizes, int n_in,
                              void* d_out, int out_size, void* d_ws, size_t ws_size,
                              hipStream_t stream) {
    const float* hiddens = (const float*)d_in[0];
    const float* query   = (const float*)d_in[1];
    const int*   mask    = (const int*)d_in[2];
    const float* W_q = (const float*)d_in[3];
    const float* b_q = (const float*)d_in[4];
    const float* W_k = (const float*)d_in[5];
    const float* W_v = (const float*)d_in[6];
    const float* W_o = (const float*)d_in[7];
    const float* b_o = (const float*)d_in[8];
    float* out = (float*)d_out;

    constexpr size_t N_H  = 8UL * 2048 * 1024;  // 16777216
    constexpr size_t N_QH = 8UL * 512 * 1024;   // 4194304
    constexpr size_t N_W  = 1024UL * 1024;      // 1048576
    char* ws = (char*)d_ws;
    short* Hb   = (short*)(ws);
    short* QHb  = (short*)(ws + N_H * 2);
    short* Wqt  = (short*)(ws + N_H * 2 + N_QH * 2);
    short* Wkt  = Wqt + N_W;
    short* Wvt  = Wkt + N_W;   // contiguous after Wkt: enables N=2048 dual GEMM
    short* Wot  = Wvt + N_W;
    short* Qb   = Wot + N_W;
    short* Kb   = Qb + N_QH;
    short* Vtb  = Kb + N_H;    // V stored transposed: [b][h][d][s]
    short* Cb   = Vtb + N_H;
    float* lseP = (float*)(Cb + N_QH);

    cvt_bf16<<<16384, 256, 0, stream>>>(hiddens, Hb, (int)N_H);
    cvt_bf16<<<4096, 256, 0, stream>>>(query, QHb, (int)N_QH);
    cvt_t4<<<dim3(32, 32, 4), dim3(32, 8), 0, stream>>>(W_q, W_k, W_v, W_o, Wqt);

    gemm128<<<dim3(8, 32), 256, 0, stream>>>(QHb, Wqt, b_q, Qb, 4096, 0);
    // fused K+V projection as one wide GEMM (N=2048), 256^2 counted-vmcnt pipeline
    gemm256<<<dim3(8, 64), 512, 0, stream>>>(Hb, Wkt, Kb, Vtb);

    attn_flash<<<dim3(4, 16, 8), 512, 0, stream>>>(Qb, Kb, Vtb, mask, Cb, lseP);

    gemm128<<<dim3(8, 32), 256, 0, stream>>>(Cb, Wot, b_o, out, 4096, 1);
    attn_amean<<<dim3(32, 8, 8), 256, 0, stream>>>(Qb, Kb, mask, lseP, out + N_QH);
}

// Round 8
// 387.068 us; speedup vs baseline: 1.1299x; 1.1299x over previous
//
#include <hip/hip_runtime.h>
#include <hip/hip_bf16.h>

// ---------------- types ----------------
using short8  = __attribute__((ext_vector_type(8))) short;   // 8 bf16 (4 VGPRs)
using short4v = __attribute__((ext_vector_type(4))) short;   // 4 bf16 (8B)
using f32x4   = __attribute__((ext_vector_type(4))) float;   // 4 fp32 acc

#define LSK 72   // LDS row stride (shorts) for Ps tile

#define GLDS(gptr, lptr) __builtin_amdgcn_global_load_lds( \
    (const __attribute__((address_space(1))) void*)(gptr), \
    (__attribute__((address_space(3))) void*)(lptr), 16, 0, 0)

#define GLDS4(gptr, lptr) __builtin_amdgcn_global_load_lds( \
    (const __attribute__((address_space(1))) void*)(gptr), \
    (__attribute__((address_space(3))) void*)(lptr), 4, 0, 0)

// top-of-iter sync: drain PREVIOUS tile's loads (keep the N just-issued in flight),
// then barrier; sched_barrier pins compute below the barrier (rule 18).
#define TOPSYNC_V(n_lit) do { \
    asm volatile("s_waitcnt vmcnt(" #n_lit ")" ::: "memory"); \
    __builtin_amdgcn_s_barrier(); \
    __builtin_amdgcn_sched_barrier(0); \
} while (0)
// end-of-iter sync: all LDS reads of cur done before anyone overwrites it next iter.
#define ENDSYNC() do { \
    __builtin_amdgcn_sched_barrier(0); \
    __builtin_amdgcn_s_barrier(); \
} while (0)

static __device__ __forceinline__ short f2b(float f) {
    unsigned u = __builtin_bit_cast(unsigned, f);
    unsigned r = (u + 0x7fffu + ((u >> 16) & 1u)) >> 16;
    return (short)r;
}

// ---------------- convert kernels ----------------
__global__ void cvt_bf16(const float* __restrict__ in, short* __restrict__ out, int n) {
    int i = (blockIdx.x * 256 + threadIdx.x) * 4;
    if (i >= n) return;
    float4 v = *(const float4*)(in + i);
    short4 o = make_short4(f2b(v.x), f2b(v.y), f2b(v.z), f2b(v.w));
    *(short4*)(out + i) = o;
}

// 4 weights f32 [1024][1024] -> Wt bf16 [N][K], dsts contiguous from Wt0
__global__ void cvt_t4(const float* __restrict__ W0, const float* __restrict__ W1,
                       const float* __restrict__ W2, const float* __restrict__ W3,
                       short* __restrict__ Wt0) {
    __shared__ short tile[32][33];
    const float* Ws[4] = {W0, W1, W2, W3};
    const float* W = Ws[blockIdx.z];
    short* Wt = Wt0 + (size_t)blockIdx.z * 1024 * 1024;
    const int K = 1024, N = 1024;
    int n0 = blockIdx.x * 32, k0 = blockIdx.y * 32;
    int tx = threadIdx.x, ty = threadIdx.y; // (32,8)
#pragma unroll
    for (int i = 0; i < 4; i++) {
        int r = ty + i * 8;
        tile[r][tx] = f2b(W[(size_t)(k0 + r) * N + n0 + tx]);
    }
    __syncthreads();
#pragma unroll
    for (int i = 0; i < 4; i++) {
        int r = ty + i * 8;
        Wt[(size_t)(n0 + r) * K + k0 + tx] = tile[tx][r];
    }
}

// ---------------- GEMM 256x256: 8-wave, counted-vmcnt pipeline, coalesced V^T ----------------
// KV projection only (M=16384, N=2048, K=1024). Grid (8,64): nx<4 -> K blocks (direct
// coalesced [m][1024] write); nx>=4 -> V blocks (LDS-transposed epilogue -> coalesced
// Vt[b][h][d][s] rows). The old per-lane 2B scatter (4KB stride) caused ~16x L2 write
// txns + 33.5MB read-for-ownership fills; transpose removes both.
__global__ __launch_bounds__(512, 1) void gemm256(
    const short* __restrict__ A, const short* __restrict__ Bt,
    short* __restrict__ CK, short* __restrict__ CVt)
{
    __shared__ short lds[65536];   // As[2][16384] | Bs[2][16384]; reused as [256][256] T-buf
    const int tid = threadIdx.x;
    const int w = tid >> 6, L = tid & 63, quad = L >> 4, l16 = L & 15;
    const int wr = w >> 2, wcn = w & 3;   // 2x4 wave grid; per-wave output 128x64

    const int lin = blockIdx.y * gridDim.x + blockIdx.x;
    const int xcd = lin & 7, idx = lin >> 3;
    const int mPer = gridDim.y >> 3;      // 64/8 = 8
    const int my = xcd * mPer + idx / gridDim.x;
    const int nx = idx % gridDim.x;
    const int n0 = nx * 256, m0 = my * 256;

    const int K = 1024;
    const int srow_in = L >> 3;                    // 0..7 within 8-row chunk
    const int sgcol   = ((L & 7) ^ srow_in) * 8;   // pre-swizzled global col (shorts)

    // 64 chunks of 8 rows x 64 cols: waves 0-3 stage A (chunks 0-31), 4-7 stage B.
    auto STAGE_ALL = [&](int buf, int kt) {
        const int k0 = kt * 64;
#pragma unroll
        for (int j = 0; j < 8; j++) {
            int c = w * 8 + j;
            if (c < 32) {
                int row = c * 8 + srow_in;
                GLDS(A + (size_t)(m0 + row) * K + k0 + sgcol, &lds[buf * 16384 + c * 512]);
            } else {
                int row = (c - 32) * 8 + srow_in;
                GLDS(Bt + (size_t)(n0 + row) * K + k0 + sgcol, &lds[32768 + buf * 16384 + (c - 32) * 512]);
            }
        }
    };

    f32x4 acc[2][4][4];
#pragma unroll
    for (int mh = 0; mh < 2; mh++)
#pragma unroll
        for (int mi = 0; mi < 4; mi++)
#pragma unroll
            for (int ni = 0; ni < 4; ni++) acc[mh][mi][ni] = (f32x4){0.f, 0.f, 0.f, 0.f};

    STAGE_ALL(0, 0);   // prologue; drained by first TOPSYNC

    for (int t = 0; t < 16; t++) {
        const int cur = t & 1;
        if (t < 15) {
            STAGE_ALL(cur ^ 1, t + 1);
            TOPSYNC_V(8);          // drain prev tile's 8, keep the 8 just issued flying
        } else {
            TOPSYNC_V(0);          // last tile: drain fully
        }
#pragma unroll
        for (int ks = 0; ks < 2; ks++) {
            const int swz = (((ks * 4) + quad) ^ (l16 & 7)) << 3;
            short8 bf[4];
#pragma unroll
            for (int ni = 0; ni < 4; ni++)
                bf[ni] = *(const short8*)&lds[32768 + cur * 16384 + (wcn * 64 + ni * 16 + l16) * 64 + swz];
#pragma unroll
            for (int mh = 0; mh < 2; mh++) {
                short8 af[4];
#pragma unroll
                for (int mi = 0; mi < 4; mi++)
                    af[mi] = *(const short8*)&lds[cur * 16384 + (wr * 128 + mh * 64 + mi * 16 + l16) * 64 + swz];
                __builtin_amdgcn_s_setprio(1);
#pragma unroll
                for (int mi = 0; mi < 4; mi++)
#pragma unroll
                    for (int ni = 0; ni < 4; ni++)
                        acc[mh][mi][ni] = __builtin_amdgcn_mfma_f32_16x16x32_bf16(af[mi], bf[ni], acc[mh][mi][ni], 0, 0, 0);
                __builtin_amdgcn_s_setprio(0);
            }
        }
        ENDSYNC();   // all reads of buf[cur] done; next iter may overwrite it
    }

    if (n0 < 1024) {
        // K half: direct coalesced [m][1024] bf16 write
#pragma unroll
        for (int mh = 0; mh < 2; mh++)
#pragma unroll
            for (int ni = 0; ni < 4; ni++) {
                int n = n0 + wcn * 64 + ni * 16 + l16;
#pragma unroll
                for (int mi = 0; mi < 4; mi++)
#pragma unroll
                    for (int r = 0; r < 4; r++) {
                        int m = m0 + wr * 128 + mh * 64 + mi * 16 + quad * 4 + r;
                        CK[(size_t)m * 1024 + n] = f2b(acc[mh][mi][ni][r]);
                    }
            }
    } else {
        // V half: transpose 256x256 through LDS (free after last ENDSYNC), then
        // write Vt[b][h][d][s] rows fully coalesced.
        // Write: granule g (4 shorts, m-major) of local-n row, XOR-swizzled by n&15.
#pragma unroll
        for (int mh = 0; mh < 2; mh++)
#pragma unroll
            for (int mi = 0; mi < 4; mi++) {
                const int g = wr * 32 + mh * 16 + mi * 4 + quad;   // m-granule 0..63
#pragma unroll
                for (int ni = 0; ni < 4; ni++) {
                    int n = wcn * 64 + ni * 16 + l16;              // local n 0..255
                    short4v v;
#pragma unroll
                    for (int r = 0; r < 4; r++) v[r] = f2b(acc[mh][mi][ni][r]);
                    *(short4v*)&lds[n * 256 + ((g ^ (n & 15)) << 2)] = v;
                }
            }
        __syncthreads();
        const int hb = (n0 - 1024) >> 6;
        const int bb = m0 >> 11, sb = m0 & 2047;
        // Readout: 2 rows per pass, 32 lanes x 16B cover each 512B row -> full lines.
#pragma unroll
        for (int i = 0; i < 16; i++) {
            int row = w * 32 + i * 2 + (L >> 5);      // local n
            int cg  = (L & 31) * 2;                   // granule pair (m-cols)
            int sw  = row & 15;
            short4v a = *(const short4v*)&lds[row * 256 + ((cg ^ sw) << 2)];
            short4v c2 = *(const short4v*)&lds[row * 256 + (((cg + 1) ^ sw) << 2)];
            short8 o;
            o[0] = a[0]; o[1] = a[1]; o[2] = a[2]; o[3] = a[3];
            o[4] = c2[0]; o[5] = c2[1]; o[6] = c2[2]; o[7] = c2[3];
            int h = hb + (row >> 6), d = row & 63;
            *(short8*)&CVt[(((size_t)bb * 16 + h) * 64 + d) * 2048 + sb + (L & 31) * 8] = o;
        }
    }
}

// ---------------- GEMM: 128m x 128n tile, BK=64, counted-vmcnt 2-phase ----------------
// Q/O projections. mode 0: bf16 [m][n]; mode 1: f32 [m][n]
__global__ __launch_bounds__(256) void gemm128(
    const short* __restrict__ A, const short* __restrict__ Bt,
    const float* __restrict__ bias, void* __restrict__ Cout,
    int M, int mode)
{
    __shared__ short As[2][128 * 64];
    __shared__ short Bs[2][128 * 64];
    const int tid = threadIdx.x;
    const int w = tid >> 6, L = tid & 63, quad = L >> 4, l16 = L & 15;
    const int wr = w >> 1, wc = w & 1;   // 2x2 wave grid, each wave owns 64x64

    const int lin = blockIdx.y * gridDim.x + blockIdx.x;
    const int xcd = lin & 7, idx = lin >> 3;
    const int mPer = gridDim.y >> 3;
    const int my = xcd * mPer + idx / gridDim.x;
    const int nx = idx % gridDim.x;
    const int n0 = nx * 128, m0 = my * 128;

    const int K = 1024;
    const int srow_in = L >> 3;                        // 0..7 within chunk
    const int sgcol   = ((L & 7) ^ (srow_in & 7)) * 8; // swizzled global col (shorts)

    auto STAGE = [&](int buf, int k0) {
#pragma unroll
        for (int j = 0; j < 8; j++) {
            int c = w * 8 + j;
            if (c < 16) {
                int row = c * 8 + srow_in;
                GLDS(A + (size_t)(m0 + row) * K + k0 + sgcol, &As[buf][c * 512]);
            } else {
                int row = (c - 16) * 8 + srow_in;
                GLDS(Bt + (size_t)(n0 + row) * K + k0 + sgcol, &Bs[buf][(c - 16) * 512]);
            }
        }
    };

    f32x4 acc[4][4];
#pragma unroll
    for (int mi = 0; mi < 4; mi++)
#pragma unroll
        for (int ni = 0; ni < 4; ni++) acc[mi][ni] = (f32x4){0.f, 0.f, 0.f, 0.f};

    STAGE(0, 0);   // prologue

    for (int t = 0; t < 16; t++) {
        const int cur = t & 1;
        if (t < 15) {
            STAGE(cur ^ 1, (t + 1) * 64);
            TOPSYNC_V(8);
        } else {
            TOPSYNC_V(0);
        }
#pragma unroll
        for (int kk = 0; kk < 64; kk += 32) {
            const int swz = (((kk >> 3) + quad) ^ (l16 & 7)) << 3;
            short8 af[4], bf[4];
#pragma unroll
            for (int mi = 0; mi < 4; mi++)
                af[mi] = *(const short8*)&As[cur][(wr * 64 + mi * 16 + l16) * 64 + swz];
#pragma unroll
            for (int ni = 0; ni < 4; ni++)
                bf[ni] = *(const short8*)&Bs[cur][(wc * 64 + ni * 16 + l16) * 64 + swz];
#pragma unroll
            for (int mi = 0; mi < 4; mi++)
#pragma unroll
                for (int ni = 0; ni < 4; ni++)
                    acc[mi][ni] = __builtin_amdgcn_mfma_f32_16x16x32_bf16(af[mi], bf[ni], acc[mi][ni], 0, 0, 0);
        }
        ENDSYNC();
    }

#pragma unroll
    for (int ni = 0; ni < 4; ni++) {
        int n = n0 + wc * 64 + ni * 16 + l16;
        float bv = bias ? bias[n] : 0.f;
#pragma unroll
        for (int mi = 0; mi < 4; mi++) {
#pragma unroll
            for (int r = 0; r < 4; r++) {
                int m = m0 + wr * 64 + mi * 16 + quad * 4 + r;
                float v = acc[mi][ni][r] + bv;
                if (mode == 1)      ((float*)Cout)[(size_t)m * 1024 + n] = v;
                else                ((short*)Cout)[(size_t)m * 1024 + n] = f2b(v);
            }
        }
    }
}

// ---------------- flash attention: t-tile=128, s-tile=128, counted-vmcnt dbuf ----------------
__global__ __launch_bounds__(512) void attn_flash(
    const short* __restrict__ Qb, const short* __restrict__ Kb, const short* __restrict__ Vtb,
    const int* __restrict__ mask, short* __restrict__ Cb, float* __restrict__ lse)
{
    __shared__ short Qs[128 * 64];
    __shared__ short Ks[2][128 * 64];      // dbuf K rows
    __shared__ short Vts[2][128 * 64];     // dbuf, two [64 d][64 s] halves each
    __shared__ short Ps[128 * LSK];
    __shared__ int   negi[2048];           // whole-row mask, staged once in prologue
    const int tid = threadIdx.x;
    const int w = tid >> 6, L = tid & 63, quad = L >> 4, l16 = L & 15;
    const int t0 = blockIdx.x * 128, h = blockIdx.y, b = blockIdx.z;
    const int S = 2048, T = 512, H = 1024;
    const int trow = w * 16;
    const int srow = L >> 3;
    const int sg   = ((L & 7) ^ srow) * 8;

    auto STAGE_KV = [&](int buf, int s0) {   // 4 glds/thread, uniform across waves
#pragma unroll
        for (int j = 0; j < 2; j++) {
            int krow = w * 16 + j * 8 + srow;
            GLDS(Kb + ((size_t)b * S + s0 + krow) * H + h * 64 + sg, &Ks[buf][(w * 16 + j * 8) * 64]);
            int c = w * 2 + j, hf = c >> 3, d0 = (c & 7) * 8;
            GLDS(Vtb + (((size_t)b * 16 + h) * 64 + d0 + srow) * S + s0 + hf * 64 + sg, &Vts[buf][c * 512]);
        }
    };

    // prologue: Q tile + whole mask row + first K/V tile; full drain once
#pragma unroll
    for (int j = 0; j < 2; j++) {
        int row = w * 16 + j * 8 + srow;
        GLDS(Qb + ((size_t)b * T + t0 + row) * H + h * 64 + sg, &Qs[(w * 16 + j * 8) * 64]);
    }
#pragma unroll
    for (int r = 0; r < 4; r++)
        GLDS4(mask + (size_t)b * S + r * 512 + w * 64 + L, &negi[r * 512 + w * 64]);
    STAGE_KV(0, 0);
    __syncthreads();

    short8 aq[2];
#pragma unroll
    for (int kk = 0; kk < 2; kk++)
        aq[kk] = *(const short8*)&Qs[(trow + l16) * 64 + ((kk * 4 + quad) ^ (l16 & 7)) * 8];

    f32x4 Oacc[4];
#pragma unroll
    for (int nt = 0; nt < 4; nt++) Oacc[nt] = (f32x4){0.f, 0.f, 0.f, 0.f};
    float lsum[4] = {0.f, 0.f, 0.f, 0.f};

    for (int it = 0; it < 16; it++) {
        const int cur = it & 1;
        if (it < 15) {
            STAGE_KV(cur ^ 1, (it + 1) * 128);
            TOPSYNC_V(4);
        } else {
            TOPSYNC_V(0);
        }
#pragma unroll
        for (int hf = 0; hf < 2; hf++) {
            // S = Q K^T for this 64-s half
            f32x4 sacc[4];
#pragma unroll
            for (int nt = 0; nt < 4; nt++) sacc[nt] = (f32x4){0.f, 0.f, 0.f, 0.f};
#pragma unroll
            for (int kk = 0; kk < 2; kk++) {
#pragma unroll
                for (int nt = 0; nt < 4; nt++) {
                    short8 bf = *(const short8*)&Ks[cur][(hf * 64 + nt * 16 + l16) * 64 + ((kk * 4 + quad) ^ (l16 & 7)) * 8];
                    sacc[nt] = __builtin_amdgcn_mfma_f32_16x16x32_bf16(aq[kk], bf, sacc[nt], 0, 0, 0);
                }
            }
            // p = exp(s/8 + neg); write Ps (wave-private rows)
#pragma unroll
            for (int nt = 0; nt < 4; nt++) {
                float ng = negi[it * 128 + hf * 64 + nt * 16 + l16] ? 0.f : -1e20f;
#pragma unroll
                for (int r = 0; r < 4; r++) {
                    float e = __expf(fmaf(sacc[nt][r], 0.125f, ng));
                    lsum[r] += e;
                    Ps[(trow + quad * 4 + r) * LSK + nt * 16 + l16] = f2b(e);
                }
            }
            // O += P V
#pragma unroll
            for (int kk = 0; kk < 2; kk++) {
                short8 af = *(const short8*)&Ps[(trow + l16) * LSK + kk * 32 + quad * 8];
#pragma unroll
                for (int nt = 0; nt < 4; nt++) {
                    short8 bf = *(const short8*)&Vts[cur][hf * 4096 + (nt * 16 + l16) * 64 + ((kk * 4 + quad) ^ (l16 & 7)) * 8];
                    Oacc[nt] = __builtin_amdgcn_mfma_f32_16x16x32_bf16(af, bf, Oacc[nt], 0, 0, 0);
                }
            }
        }
        ENDSYNC();
    }
    // rowsum reduce across the 16 lanes of each quad-group
#pragma unroll
    for (int r = 0; r < 4; r++) {
#pragma unroll
        for (int off = 1; off < 16; off <<= 1)
            lsum[r] += __shfl_xor(lsum[r], off, 64);
    }
#pragma unroll
    for (int r = 0; r < 4; r++) {
        float inv = 1.0f / lsum[r];
        int t = t0 + trow + quad * 4 + r;
#pragma unroll
        for (int nt = 0; nt < 4; nt++) {
            int d = nt * 16 + l16;
            Cb[((size_t)b * T + t) * H + h * 64 + d] = f2b(Oacc[nt][r] * inv);
        }
        if (l16 == 0)
            lse[((size_t)b * 16 + h) * T + t] = __logf(lsum[r]);
    }
}

// ---------------- a_mean: out[b][t][s] = mean_h exp(qk/8 + neg - lse_h) ----------------
__global__ __launch_bounds__(256) void attn_amean(
    const short* __restrict__ Qb, const short* __restrict__ Kb,
    const int* __restrict__ mask, const float* __restrict__ lse, float* __restrict__ outA)
{
    __shared__ short Qs[2][64 * 64];
    __shared__ short Ks[2][64 * 64];
    __shared__ float neg[64];
    __shared__ float lss[16 * 64];
    const int tid = threadIdx.x;
    const int w = tid >> 6, L = tid & 63, quad = L >> 4, l16 = L & 15;
    const int s0 = blockIdx.x * 64, t0 = blockIdx.y * 64, b = blockIdx.z;
    const int S = 2048, T = 512, H = 1024;
    const int srow = L >> 3;
    const int sg   = ((L & 7) ^ srow) * 8;

    auto STAGE_QK = [&](int buf, int h) {   // 4 glds/thread, uniform
#pragma unroll
        for (int j = 0; j < 2; j++) {
            int row = w * 16 + j * 8 + srow;
            GLDS(Qb + ((size_t)b * T + t0 + row) * H + h * 64 + sg, &Qs[buf][(w * 16 + j * 8) * 64]);
            GLDS(Kb + ((size_t)b * S + s0 + row) * H + h * 64 + sg, &Ks[buf][(w * 16 + j * 8) * 64]);
        }
    };

    if (tid < 64) neg[tid] = mask[(size_t)b * S + s0 + tid] ? 0.f : -1e20f;
    for (int i = tid; i < 16 * 64; i += 256) {
        int hh = i >> 6, tt = i & 63;
        lss[i] = lse[((size_t)b * 16 + hh) * T + t0 + tt];
    }
    STAGE_QK(0, 0);
    __syncthreads();   // neg/lss settled, head-0 staged, vmcnt drained

    float am[4][4] = {};
    for (int h = 0; h < 16; h++) {
        const int cur = h & 1;
        if (h < 15) {
            STAGE_QK(cur ^ 1, h + 1);
            TOPSYNC_V(4);
        } else {
            TOPSYNC_V(0);
        }
        short8 aq[2];
#pragma unroll
        for (int kk = 0; kk < 2; kk++)
            aq[kk] = *(const short8*)&Qs[cur][(w * 16 + l16) * 64 + ((kk * 4 + quad) ^ (l16 & 7)) * 8];
        f32x4 sacc[4];
#pragma unroll
        for (int nt = 0; nt < 4; nt++) sacc[nt] = (f32x4){0.f, 0.f, 0.f, 0.f};
#pragma unroll
        for (int kk = 0; kk < 2; kk++) {
#pragma unroll
            for (int nt = 0; nt < 4; nt++) {
                short8 bf = *(const short8*)&Ks[cur][(nt * 16 + l16) * 64 + ((kk * 4 + quad) ^ (l16 & 7)) * 8];
                sacc[nt] = __builtin_amdgcn_mfma_f32_16x16x32_bf16(aq[kk], bf, sacc[nt], 0, 0, 0);
            }
        }
#pragma unroll
        for (int nt = 0; nt < 4; nt++) {
            float ng = neg[nt * 16 + l16];
#pragma unroll
            for (int r = 0; r < 4; r++) {
                int trow = w * 16 + quad * 4 + r;
                am[nt][r] += __expf(fmaf(sacc[nt][r], 0.125f, ng - lss[h * 64 + trow]));
            }
        }
        ENDSYNC();
    }
#pragma unroll
    for (int r = 0; r < 4; r++) {
        int t = t0 + w * 16 + quad * 4 + r;
#pragma unroll
        for (int nt = 0; nt < 4; nt++) {
            int s = s0 + nt * 16 + l16;
            outA[((size_t)b * T + t) * S + s] = am[nt][r] * 0.0625f;
        }
    }
}

// ---------------- launch ----------------
extern "C" void kernel_launch(void* const* d_in, const int* in_sizes, int n_in,
                              void* d_out, int out_size, void* d_ws, size_t ws_size,
                              hipStream_t stream) {
    const float* hiddens = (const float*)d_in[0];
    const float* query   = (const float*)d_in[1];
    const int*   mask    = (const int*)d_in[2];
    const float* W_q = (const float*)d_in[3];
    const float* b_q = (const float*)d_in[4];
    const float* W_k = (const float*)d_in[5];
    const float* W_v = (const float*)d_in[6];
    const float* W_o = (const float*)d_in[7];
    const float* b_o = (const float*)d_in[8];
    float* out = (float*)d_out;

    constexpr size_t N_H  = 8UL * 2048 * 1024;  // 16777216
    constexpr size_t N_QH = 8UL * 512 * 1024;   // 4194304
    constexpr size_t N_W  = 1024UL * 1024;      // 1048576
    char* ws = (char*)d_ws;
    short* Hb   = (short*)(ws);
    short* QHb  = (short*)(ws + N_H * 2);
    short* Wqt  = (short*)(ws + N_H * 2 + N_QH * 2);
    short* Wkt  = Wqt + N_W;
    short* Wvt  = Wkt + N_W;   // contiguous after Wkt: enables N=2048 dual GEMM
    short* Wot  = Wvt + N_W;
    short* Qb   = Wot + N_W;
    short* Kb   = Qb + N_QH;
    short* Vtb  = Kb + N_H;    // V stored transposed: [b][h][d][s]
    short* Cb   = Vtb + N_H;
    float* lseP = (float*)(Cb + N_QH);

    cvt_bf16<<<16384, 256, 0, stream>>>(hiddens, Hb, (int)N_H);
    cvt_bf16<<<4096, 256, 0, stream>>>(query, QHb, (int)N_QH);
    cvt_t4<<<dim3(32, 32, 4), dim3(32, 8), 0, stream>>>(W_q, W_k, W_v, W_o, Wqt);

    gemm128<<<dim3(8, 32), 256, 0, stream>>>(QHb, Wqt, b_q, Qb, 4096, 0);
    // fused K+V projection as one wide GEMM (N=2048), 256^2 counted-vmcnt pipeline
    gemm256<<<dim3(8, 64), 512, 0, stream>>>(Hb, Wkt, Kb, Vtb);

    attn_flash<<<dim3(4, 16, 8), 512, 0, stream>>>(Qb, Kb, Vtb, mask, Cb, lseP);

    gemm128<<<dim3(8, 32), 256, 0, stream>>>(Cb, Wot, b_o, out, 4096, 1);
    attn_amean<<<dim3(32, 8, 8), 256, 0, stream>>>(Qb, Kb, mask, lseP, out + N_QH);
}

// Round 9
// 373.689 us; speedup vs baseline: 1.1703x; 1.0358x over previous
//
#include <hip/hip_runtime.h>
#include <hip/hip_bf16.h>

// ---------------- types ----------------
using short8  = __attribute__((ext_vector_type(8))) short;   // 8 bf16 (4 VGPRs)
using short4v = __attribute__((ext_vector_type(4))) short;   // 4 bf16 (8B)
using f32x4   = __attribute__((ext_vector_type(4))) float;   // 4 fp32 acc

#define LSK 72   // LDS row stride (shorts) for Ps tile

#define GLDS(gptr, lptr) __builtin_amdgcn_global_load_lds( \
    (const __attribute__((address_space(1))) void*)(gptr), \
    (__attribute__((address_space(3))) void*)(lptr), 16, 0, 0)

#define GLDS4(gptr, lptr) __builtin_amdgcn_global_load_lds( \
    (const __attribute__((address_space(1))) void*)(gptr), \
    (__attribute__((address_space(3))) void*)(lptr), 4, 0, 0)

// top-of-iter sync: drain PREVIOUS tile's loads (keep the N just-issued in flight),
// then barrier; sched_barrier pins compute below the barrier (rule 18).
#define TOPSYNC_V(n_lit) do { \
    asm volatile("s_waitcnt vmcnt(" #n_lit ")" ::: "memory"); \
    __builtin_amdgcn_s_barrier(); \
    __builtin_amdgcn_sched_barrier(0); \
} while (0)
// end-of-iter sync: all LDS reads of cur done before anyone overwrites it next iter.
#define ENDSYNC() do { \
    __builtin_amdgcn_sched_barrier(0); \
    __builtin_amdgcn_s_barrier(); \
} while (0)

static __device__ __forceinline__ short f2b(float f) {
    unsigned u = __builtin_bit_cast(unsigned, f);
    unsigned r = (u + 0x7fffu + ((u >> 16) & 1u)) >> 16;
    return (short)r;
}

// ---------------- convert kernels ----------------
__global__ void cvt_bf16(const float* __restrict__ in, short* __restrict__ out, int n) {
    int i = (blockIdx.x * 256 + threadIdx.x) * 4;
    if (i >= n) return;
    float4 v = *(const float4*)(in + i);
    short4 o = make_short4(f2b(v.x), f2b(v.y), f2b(v.z), f2b(v.w));
    *(short4*)(out + i) = o;
}

// 4 weights f32 [1024][1024] -> Wt bf16 [N][K], dsts contiguous from Wt0
__global__ void cvt_t4(const float* __restrict__ W0, const float* __restrict__ W1,
                       const float* __restrict__ W2, const float* __restrict__ W3,
                       short* __restrict__ Wt0) {
    __shared__ short tile[32][33];
    const float* Ws[4] = {W0, W1, W2, W3};
    const float* W = Ws[blockIdx.z];
    short* Wt = Wt0 + (size_t)blockIdx.z * 1024 * 1024;
    const int K = 1024, N = 1024;
    int n0 = blockIdx.x * 32, k0 = blockIdx.y * 32;
    int tx = threadIdx.x, ty = threadIdx.y; // (32,8)
#pragma unroll
    for (int i = 0; i < 4; i++) {
        int r = ty + i * 8;
        tile[r][tx] = f2b(W[(size_t)(k0 + r) * N + n0 + tx]);
    }
    __syncthreads();
#pragma unroll
    for (int i = 0; i < 4; i++) {
        int r = ty + i * 8;
        Wt[(size_t)(n0 + r) * K + k0 + tx] = tile[tx][r];
    }
}

// ---------------- GEMM 256x256: 8-wave, counted-vmcnt pipeline, coalesced V^T ----------------
// KV projection only (M=16384, N=2048, K=1024). Grid (8,64): nx<4 -> K blocks (direct
// coalesced [m][1024] write); nx>=4 -> V blocks (LDS-transposed epilogue -> coalesced
// Vt[b][h][d][s] rows).
__global__ __launch_bounds__(512, 1) void gemm256(
    const short* __restrict__ A, const short* __restrict__ Bt,
    short* __restrict__ CK, short* __restrict__ CVt)
{
    __shared__ short lds[65536];   // As[2][16384] | Bs[2][16384]; reused as [256][256] T-buf
    const int tid = threadIdx.x;
    const int w = tid >> 6, L = tid & 63, quad = L >> 4, l16 = L & 15;
    const int wr = w >> 2, wcn = w & 3;   // 2x4 wave grid; per-wave output 128x64

    const int lin = blockIdx.y * gridDim.x + blockIdx.x;
    const int xcd = lin & 7, idx = lin >> 3;
    const int mPer = gridDim.y >> 3;      // 64/8 = 8
    const int my = xcd * mPer + idx / gridDim.x;
    const int nx = idx % gridDim.x;
    const int n0 = nx * 256, m0 = my * 256;

    const int K = 1024;
    const int srow_in = L >> 3;                    // 0..7 within 8-row chunk
    const int sgcol   = ((L & 7) ^ srow_in) * 8;   // pre-swizzled global col (shorts)

    // 64 chunks of 8 rows x 64 cols: waves 0-3 stage A (chunks 0-31), 4-7 stage B.
    auto STAGE_ALL = [&](int buf, int kt) {
        const int k0 = kt * 64;
#pragma unroll
        for (int j = 0; j < 8; j++) {
            int c = w * 8 + j;
            if (c < 32) {
                int row = c * 8 + srow_in;
                GLDS(A + (size_t)(m0 + row) * K + k0 + sgcol, &lds[buf * 16384 + c * 512]);
            } else {
                int row = (c - 32) * 8 + srow_in;
                GLDS(Bt + (size_t)(n0 + row) * K + k0 + sgcol, &lds[32768 + buf * 16384 + (c - 32) * 512]);
            }
        }
    };

    f32x4 acc[2][4][4];
#pragma unroll
    for (int mh = 0; mh < 2; mh++)
#pragma unroll
        for (int mi = 0; mi < 4; mi++)
#pragma unroll
            for (int ni = 0; ni < 4; ni++) acc[mh][mi][ni] = (f32x4){0.f, 0.f, 0.f, 0.f};

    STAGE_ALL(0, 0);   // prologue; drained by first TOPSYNC

    for (int t = 0; t < 16; t++) {
        const int cur = t & 1;
        if (t < 15) {
            STAGE_ALL(cur ^ 1, t + 1);
            TOPSYNC_V(8);          // drain prev tile's 8, keep the 8 just issued flying
        } else {
            TOPSYNC_V(0);          // last tile: drain fully
        }
#pragma unroll
        for (int ks = 0; ks < 2; ks++) {
            const int swz = (((ks * 4) + quad) ^ (l16 & 7)) << 3;
            short8 bf[4];
#pragma unroll
            for (int ni = 0; ni < 4; ni++)
                bf[ni] = *(const short8*)&lds[32768 + cur * 16384 + (wcn * 64 + ni * 16 + l16) * 64 + swz];
#pragma unroll
            for (int mh = 0; mh < 2; mh++) {
                short8 af[4];
#pragma unroll
                for (int mi = 0; mi < 4; mi++)
                    af[mi] = *(const short8*)&lds[cur * 16384 + (wr * 128 + mh * 64 + mi * 16 + l16) * 64 + swz];
                __builtin_amdgcn_s_setprio(1);
#pragma unroll
                for (int mi = 0; mi < 4; mi++)
#pragma unroll
                    for (int ni = 0; ni < 4; ni++)
                        acc[mh][mi][ni] = __builtin_amdgcn_mfma_f32_16x16x32_bf16(af[mi], bf[ni], acc[mh][mi][ni], 0, 0, 0);
                __builtin_amdgcn_s_setprio(0);
            }
        }
        ENDSYNC();   // all reads of buf[cur] done; next iter may overwrite it
    }

    if (n0 < 1024) {
        // K half: direct coalesced [m][1024] bf16 write
#pragma unroll
        for (int mh = 0; mh < 2; mh++)
#pragma unroll
            for (int ni = 0; ni < 4; ni++) {
                int n = n0 + wcn * 64 + ni * 16 + l16;
#pragma unroll
                for (int mi = 0; mi < 4; mi++)
#pragma unroll
                    for (int r = 0; r < 4; r++) {
                        int m = m0 + wr * 128 + mh * 64 + mi * 16 + quad * 4 + r;
                        CK[(size_t)m * 1024 + n] = f2b(acc[mh][mi][ni][r]);
                    }
            }
    } else {
        // V half: transpose 256x256 through LDS (free after last ENDSYNC), then
        // write Vt[b][h][d][s] rows fully coalesced.
#pragma unroll
        for (int mh = 0; mh < 2; mh++)
#pragma unroll
            for (int mi = 0; mi < 4; mi++) {
                const int g = wr * 32 + mh * 16 + mi * 4 + quad;   // m-granule 0..63
#pragma unroll
                for (int ni = 0; ni < 4; ni++) {
                    int n = wcn * 64 + ni * 16 + l16;              // local n 0..255
                    short4v v;
#pragma unroll
                    for (int r = 0; r < 4; r++) v[r] = f2b(acc[mh][mi][ni][r]);
                    *(short4v*)&lds[n * 256 + ((g ^ (n & 15)) << 2)] = v;
                }
            }
        __syncthreads();
        const int hb = (n0 - 1024) >> 6;
        const int bb = m0 >> 11, sb = m0 & 2047;
#pragma unroll
        for (int i = 0; i < 16; i++) {
            int row = w * 32 + i * 2 + (L >> 5);      // local n
            int cg  = (L & 31) * 2;                   // granule pair (m-cols)
            int sw  = row & 15;
            short4v a = *(const short4v*)&lds[row * 256 + ((cg ^ sw) << 2)];
            short4v c2 = *(const short4v*)&lds[row * 256 + (((cg + 1) ^ sw) << 2)];
            short8 o;
            o[0] = a[0]; o[1] = a[1]; o[2] = a[2]; o[3] = a[3];
            o[4] = c2[0]; o[5] = c2[1]; o[6] = c2[2]; o[7] = c2[3];
            int h = hb + (row >> 6), d = row & 63;
            *(short8*)&CVt[(((size_t)bb * 16 + h) * 64 + d) * 2048 + sb + (L & 31) * 8] = o;
        }
    }
}

// ---------------- GEMM: 128m x 128n tile, BK=64, counted-vmcnt 2-phase ----------------
// Q/O projections. mode 0: bf16 [m][n]; mode 1: f32 [m][n]
__global__ __launch_bounds__(256) void gemm128(
    const short* __restrict__ A, const short* __restrict__ Bt,
    const float* __restrict__ bias, void* __restrict__ Cout,
    int M, int mode)
{
    __shared__ short As[2][128 * 64];
    __shared__ short Bs[2][128 * 64];
    const int tid = threadIdx.x;
    const int w = tid >> 6, L = tid & 63, quad = L >> 4, l16 = L & 15;
    const int wr = w >> 1, wc = w & 1;   // 2x2 wave grid, each wave owns 64x64

    const int lin = blockIdx.y * gridDim.x + blockIdx.x;
    const int xcd = lin & 7, idx = lin >> 3;
    const int mPer = gridDim.y >> 3;
    const int my = xcd * mPer + idx / gridDim.x;
    const int nx = idx % gridDim.x;
    const int n0 = nx * 128, m0 = my * 128;

    const int K = 1024;
    const int srow_in = L >> 3;                        // 0..7 within chunk
    const int sgcol   = ((L & 7) ^ (srow_in & 7)) * 8; // swizzled global col (shorts)

    auto STAGE = [&](int buf, int k0) {
#pragma unroll
        for (int j = 0; j < 8; j++) {
            int c = w * 8 + j;
            if (c < 16) {
                int row = c * 8 + srow_in;
                GLDS(A + (size_t)(m0 + row) * K + k0 + sgcol, &As[buf][c * 512]);
            } else {
                int row = (c - 16) * 8 + srow_in;
                GLDS(Bt + (size_t)(n0 + row) * K + k0 + sgcol, &Bs[buf][(c - 16) * 512]);
            }
        }
    };

    f32x4 acc[4][4];
#pragma unroll
    for (int mi = 0; mi < 4; mi++)
#pragma unroll
        for (int ni = 0; ni < 4; ni++) acc[mi][ni] = (f32x4){0.f, 0.f, 0.f, 0.f};

    STAGE(0, 0);   // prologue

    for (int t = 0; t < 16; t++) {
        const int cur = t & 1;
        if (t < 15) {
            STAGE(cur ^ 1, (t + 1) * 64);
            TOPSYNC_V(8);
        } else {
            TOPSYNC_V(0);
        }
#pragma unroll
        for (int kk = 0; kk < 64; kk += 32) {
            const int swz = (((kk >> 3) + quad) ^ (l16 & 7)) << 3;
            short8 af[4], bf[4];
#pragma unroll
            for (int mi = 0; mi < 4; mi++)
                af[mi] = *(const short8*)&As[cur][(wr * 64 + mi * 16 + l16) * 64 + swz];
#pragma unroll
            for (int ni = 0; ni < 4; ni++)
                bf[ni] = *(const short8*)&Bs[cur][(wc * 64 + ni * 16 + l16) * 64 + swz];
#pragma unroll
            for (int mi = 0; mi < 4; mi++)
#pragma unroll
                for (int ni = 0; ni < 4; ni++)
                    acc[mi][ni] = __builtin_amdgcn_mfma_f32_16x16x32_bf16(af[mi], bf[ni], acc[mi][ni], 0, 0, 0);
        }
        ENDSYNC();
    }

#pragma unroll
    for (int ni = 0; ni < 4; ni++) {
        int n = n0 + wc * 64 + ni * 16 + l16;
        float bv = bias ? bias[n] : 0.f;
#pragma unroll
        for (int mi = 0; mi < 4; mi++) {
#pragma unroll
            for (int r = 0; r < 4; r++) {
                int m = m0 + wr * 64 + mi * 16 + quad * 4 + r;
                float v = acc[mi][ni][r] + bv;
                if (mode == 1)      ((float*)Cout)[(size_t)m * 1024 + n] = v;
                else                ((short*)Cout)[(size_t)m * 1024 + n] = f2b(v);
            }
        }
    }
}

// ---------------- flash attention: t-tile=256, s-tile=128, counted-vmcnt dbuf ----------------
// t-tile 128->256: halves K/V global reads (each K/V tile feeds 256 Q-rows), doubles
// MFMA per staged byte. 8 waves, each owns 32 t-rows. LDS ~140KB -> 1 block/CU (same).
__global__ __launch_bounds__(512) void attn_flash(
    const short* __restrict__ Qb, const short* __restrict__ Kb, const short* __restrict__ Vtb,
    const int* __restrict__ mask, short* __restrict__ Cb, float* __restrict__ lse)
{
    __shared__ short Qs[256 * 64];
    __shared__ short Ks[2][128 * 64];      // dbuf K rows
    __shared__ short Vts[2][128 * 64];     // dbuf, two [64 d][64 s] halves each
    __shared__ short Ps[256 * LSK];
    __shared__ int   negi[2048];           // whole-row mask, staged once in prologue
    const int tid = threadIdx.x;
    const int w = tid >> 6, L = tid & 63, quad = L >> 4, l16 = L & 15;
    const int t0 = blockIdx.x * 256, h = blockIdx.y, b = blockIdx.z;
    const int S = 2048, T = 512, H = 1024;
    const int trow = w * 32;
    const int srow = L >> 3;
    const int sg   = ((L & 7) ^ srow) * 8;

    auto STAGE_KV = [&](int buf, int s0) {   // 4 glds/thread, uniform across waves
#pragma unroll
        for (int j = 0; j < 2; j++) {
            int krow = w * 16 + j * 8 + srow;
            GLDS(Kb + ((size_t)b * S + s0 + krow) * H + h * 64 + sg, &Ks[buf][(w * 16 + j * 8) * 64]);
            int c = w * 2 + j, hf = c >> 3, d0 = (c & 7) * 8;
            GLDS(Vtb + (((size_t)b * 16 + h) * 64 + d0 + srow) * S + s0 + hf * 64 + sg, &Vts[buf][c * 512]);
        }
    };

    // prologue: Q tile [256][64] (4 chunks/wave) + mask row + first K/V tile
#pragma unroll
    for (int j = 0; j < 4; j++) {
        int row = w * 32 + j * 8 + srow;
        GLDS(Qb + ((size_t)b * T + t0 + row) * H + h * 64 + sg, &Qs[(w * 32 + j * 8) * 64]);
    }
#pragma unroll
    for (int r = 0; r < 4; r++)
        GLDS4(mask + (size_t)b * S + r * 512 + w * 64 + L, &negi[r * 512 + w * 64]);
    STAGE_KV(0, 0);
    __syncthreads();

    short8 aq[2][2];   // [mt][kk]
#pragma unroll
    for (int mt = 0; mt < 2; mt++)
#pragma unroll
        for (int kk = 0; kk < 2; kk++)
            aq[mt][kk] = *(const short8*)&Qs[(trow + mt * 16 + l16) * 64 + ((kk * 4 + quad) ^ (l16 & 7)) * 8];

    f32x4 Oacc[2][4];
#pragma unroll
    for (int mt = 0; mt < 2; mt++)
#pragma unroll
        for (int nt = 0; nt < 4; nt++) Oacc[mt][nt] = (f32x4){0.f, 0.f, 0.f, 0.f};
    float lsum[2][4] = {};

    for (int it = 0; it < 16; it++) {
        const int cur = it & 1;
        if (it < 15) {
            STAGE_KV(cur ^ 1, (it + 1) * 128);
            TOPSYNC_V(4);
        } else {
            TOPSYNC_V(0);
        }
#pragma unroll
        for (int hf = 0; hf < 2; hf++) {
            // S = Q K^T for this 64-s half (both 16-row m-tiles share each K frag)
            f32x4 sacc[2][4];
#pragma unroll
            for (int mt = 0; mt < 2; mt++)
#pragma unroll
                for (int nt = 0; nt < 4; nt++) sacc[mt][nt] = (f32x4){0.f, 0.f, 0.f, 0.f};
#pragma unroll
            for (int kk = 0; kk < 2; kk++) {
#pragma unroll
                for (int nt = 0; nt < 4; nt++) {
                    short8 bf = *(const short8*)&Ks[cur][(hf * 64 + nt * 16 + l16) * 64 + ((kk * 4 + quad) ^ (l16 & 7)) * 8];
#pragma unroll
                    for (int mt = 0; mt < 2; mt++)
                        sacc[mt][nt] = __builtin_amdgcn_mfma_f32_16x16x32_bf16(aq[mt][kk], bf, sacc[mt][nt], 0, 0, 0);
                }
            }
            // p = exp(s/8 + neg); write Ps (wave-private rows trow..trow+31)
#pragma unroll
            for (int mt = 0; mt < 2; mt++)
#pragma unroll
                for (int nt = 0; nt < 4; nt++) {
                    float ng = negi[it * 128 + hf * 64 + nt * 16 + l16] ? 0.f : -1e20f;
#pragma unroll
                    for (int r = 0; r < 4; r++) {
                        float e = __expf(fmaf(sacc[mt][nt][r], 0.125f, ng));
                        lsum[mt][r] += e;
                        Ps[(trow + mt * 16 + quad * 4 + r) * LSK + nt * 16 + l16] = f2b(e);
                    }
                }
            // O += P V
#pragma unroll
            for (int kk = 0; kk < 2; kk++) {
                short8 af[2];
#pragma unroll
                for (int mt = 0; mt < 2; mt++)
                    af[mt] = *(const short8*)&Ps[(trow + mt * 16 + l16) * LSK + kk * 32 + quad * 8];
#pragma unroll
                for (int nt = 0; nt < 4; nt++) {
                    short8 bf = *(const short8*)&Vts[cur][hf * 4096 + (nt * 16 + l16) * 64 + ((kk * 4 + quad) ^ (l16 & 7)) * 8];
#pragma unroll
                    for (int mt = 0; mt < 2; mt++)
                        Oacc[mt][nt] = __builtin_amdgcn_mfma_f32_16x16x32_bf16(af[mt], bf, Oacc[mt][nt], 0, 0, 0);
                }
            }
        }
        ENDSYNC();
    }
    // rowsum reduce across the 16 lanes of each quad-group
#pragma unroll
    for (int mt = 0; mt < 2; mt++)
#pragma unroll
        for (int r = 0; r < 4; r++) {
#pragma unroll
            for (int off = 1; off < 16; off <<= 1)
                lsum[mt][r] += __shfl_xor(lsum[mt][r], off, 64);
        }
#pragma unroll
    for (int mt = 0; mt < 2; mt++)
#pragma unroll
        for (int r = 0; r < 4; r++) {
            float inv = 1.0f / lsum[mt][r];
            int t = t0 + trow + mt * 16 + quad * 4 + r;
#pragma unroll
            for (int nt = 0; nt < 4; nt++) {
                int d = nt * 16 + l16;
                Cb[((size_t)b * T + t) * H + h * 64 + d] = f2b(Oacc[mt][nt][r] * inv);
            }
            if (l16 == 0)
                lse[((size_t)b * 16 + h) * T + t] = __logf(lsum[mt][r]);
        }
}

// ---------------- a_mean: out[b][t][s] = mean_h exp(qk/8 + neg - lse_h) ----------------
// tiles 64x64 -> 128x128 (512 thr): Q redundancy x32->x16, K x8->x4 (536->268 MB).
__global__ __launch_bounds__(512) void attn_amean(
    const short* __restrict__ Qb, const short* __restrict__ Kb,
    const int* __restrict__ mask, const float* __restrict__ lse, float* __restrict__ outA)
{
    __shared__ short Qs[2][128 * 64];
    __shared__ short Ks[2][128 * 64];
    __shared__ float neg[128];
    __shared__ float lss[16 * 128];
    const int tid = threadIdx.x;
    const int w = tid >> 6, L = tid & 63, quad = L >> 4, l16 = L & 15;
    const int s0 = blockIdx.x * 128, t0 = blockIdx.y * 128, b = blockIdx.z;
    const int S = 2048, T = 512, H = 1024;
    const int srow = L >> 3;
    const int sg   = ((L & 7) ^ srow) * 8;

    auto STAGE_QK = [&](int buf, int h) {   // 4 glds/thread, uniform (8 waves x 2j x 8 rows = 128)
#pragma unroll
        for (int j = 0; j < 2; j++) {
            int row = w * 16 + j * 8 + srow;
            GLDS(Qb + ((size_t)b * T + t0 + row) * H + h * 64 + sg, &Qs[buf][(w * 16 + j * 8) * 64]);
            GLDS(Kb + ((size_t)b * S + s0 + row) * H + h * 64 + sg, &Ks[buf][(w * 16 + j * 8) * 64]);
        }
    };

    if (tid < 128) neg[tid] = mask[(size_t)b * S + s0 + tid] ? 0.f : -1e20f;
    for (int i = tid; i < 16 * 128; i += 512) {
        int hh = i >> 7, tt = i & 127;
        lss[i] = lse[((size_t)b * 16 + hh) * T + t0 + tt];
    }
    STAGE_QK(0, 0);
    __syncthreads();   // neg/lss settled, head-0 staged, vmcnt drained

    float am[8][4] = {};
    for (int h = 0; h < 16; h++) {
        const int cur = h & 1;
        if (h < 15) {
            STAGE_QK(cur ^ 1, h + 1);
            TOPSYNC_V(4);
        } else {
            TOPSYNC_V(0);
        }
        short8 aq[2];
#pragma unroll
        for (int kk = 0; kk < 2; kk++)
            aq[kk] = *(const short8*)&Qs[cur][(w * 16 + l16) * 64 + ((kk * 4 + quad) ^ (l16 & 7)) * 8];
        f32x4 sacc[8];
#pragma unroll
        for (int nt = 0; nt < 8; nt++) sacc[nt] = (f32x4){0.f, 0.f, 0.f, 0.f};
#pragma unroll
        for (int kk = 0; kk < 2; kk++) {
#pragma unroll
            for (int nt = 0; nt < 8; nt++) {
                short8 bf = *(const short8*)&Ks[cur][(nt * 16 + l16) * 64 + ((kk * 4 + quad) ^ (l16 & 7)) * 8];
                sacc[nt] = __builtin_amdgcn_mfma_f32_16x16x32_bf16(aq[kk], bf, sacc[nt], 0, 0, 0);
            }
        }
#pragma unroll
        for (int nt = 0; nt < 8; nt++) {
            float ng = neg[nt * 16 + l16];
#pragma unroll
            for (int r = 0; r < 4; r++) {
                int trow = w * 16 + quad * 4 + r;
                am[nt][r] += __expf(fmaf(sacc[nt][r], 0.125f, ng - lss[h * 128 + trow]));
            }
        }
        ENDSYNC();
    }
#pragma unroll
    for (int r = 0; r < 4; r++) {
        int t = t0 + w * 16 + quad * 4 + r;
#pragma unroll
        for (int nt = 0; nt < 8; nt++) {
            int s = s0 + nt * 16 + l16;
            outA[((size_t)b * T + t) * S + s] = am[nt][r] * 0.0625f;
        }
    }
}

// ---------------- launch ----------------
extern "C" void kernel_launch(void* const* d_in, const int* in_sizes, int n_in,
                              void* d_out, int out_size, void* d_ws, size_t ws_size,
                              hipStream_t stream) {
    const float* hiddens = (const float*)d_in[0];
    const float* query   = (const float*)d_in[1];
    const int*   mask    = (const int*)d_in[2];
    const float* W_q = (const float*)d_in[3];
    const float* b_q = (const float*)d_in[4];
    const float* W_k = (const float*)d_in[5];
    const float* W_v = (const float*)d_in[6];
    const float* W_o = (const float*)d_in[7];
    const float* b_o = (const float*)d_in[8];
    float* out = (float*)d_out;

    constexpr size_t N_H  = 8UL * 2048 * 1024;  // 16777216
    constexpr size_t N_QH = 8UL * 512 * 1024;   // 4194304
    constexpr size_t N_W  = 1024UL * 1024;      // 1048576
    char* ws = (char*)d_ws;
    short* Hb   = (short*)(ws);
    short* QHb  = (short*)(ws + N_H * 2);
    short* Wqt  = (short*)(ws + N_H * 2 + N_QH * 2);
    short* Wkt  = Wqt + N_W;
    short* Wvt  = Wkt + N_W;   // contiguous after Wkt: enables N=2048 dual GEMM
    short* Wot  = Wvt + N_W;
    short* Qb   = Wot + N_W;
    short* Kb   = Qb + N_QH;
    short* Vtb  = Kb + N_H;    // V stored transposed: [b][h][d][s]
    short* Cb   = Vtb + N_H;
    float* lseP = (float*)(Cb + N_QH);

    cvt_bf16<<<16384, 256, 0, stream>>>(hiddens, Hb, (int)N_H);
    cvt_bf16<<<4096, 256, 0, stream>>>(query, QHb, (int)N_QH);
    cvt_t4<<<dim3(32, 32, 4), dim3(32, 8), 0, stream>>>(W_q, W_k, W_v, W_o, Wqt);

    gemm128<<<dim3(8, 32), 256, 0, stream>>>(QHb, Wqt, b_q, Qb, 4096, 0);
    // fused K+V projection as one wide GEMM (N=2048), 256^2 counted-vmcnt pipeline
    gemm256<<<dim3(8, 64), 512, 0, stream>>>(Hb, Wkt, Kb, Vtb);

    attn_flash<<<dim3(2, 16, 8), 512, 0, stream>>>(Qb, Kb, Vtb, mask, Cb, lseP);

    gemm128<<<dim3(8, 32), 256, 0, stream>>>(Cb, Wot, b_o, out, 4096, 1);
    attn_amean<<<dim3(16, 4, 8), 512, 0, stream>>>(Qb, Kb, mask, lseP, out + N_QH);
}

// Round 10
// 367.391 us; speedup vs baseline: 1.1904x; 1.0171x over previous
//
#include <hip/hip_runtime.h>
#include <hip/hip_bf16.h>

// ---------------- types ----------------
using short8  = __attribute__((ext_vector_type(8))) short;   // 8 bf16 (4 VGPRs)
using short4v = __attribute__((ext_vector_type(4))) short;   // 4 bf16 (8B)
using f32x4   = __attribute__((ext_vector_type(4))) float;   // 4 fp32 acc

#define LSK 72   // LDS row stride (shorts) for Ps tile

#define GLDS(gptr, lptr) __builtin_amdgcn_global_load_lds( \
    (const __attribute__((address_space(1))) void*)(gptr), \
    (__attribute__((address_space(3))) void*)(lptr), 16, 0, 0)

#define GLDS4(gptr, lptr) __builtin_amdgcn_global_load_lds( \
    (const __attribute__((address_space(1))) void*)(gptr), \
    (__attribute__((address_space(3))) void*)(lptr), 4, 0, 0)

// top-of-iter sync: drain PREVIOUS tile's loads (keep the N just-issued in flight),
// then barrier; sched_barrier pins compute below the barrier (rule 18).
#define TOPSYNC_V(n_lit) do { \
    asm volatile("s_waitcnt vmcnt(" #n_lit ")" ::: "memory"); \
    __builtin_amdgcn_s_barrier(); \
    __builtin_amdgcn_sched_barrier(0); \
} while (0)
// end-of-iter sync: all LDS reads of cur done before anyone overwrites it next iter.
#define ENDSYNC() do { \
    __builtin_amdgcn_sched_barrier(0); \
    __builtin_amdgcn_s_barrier(); \
} while (0)

static __device__ __forceinline__ short f2b(float f) {
    unsigned u = __builtin_bit_cast(unsigned, f);
    unsigned r = (u + 0x7fffu + ((u >> 16) & 1u)) >> 16;
    return (short)r;
}

// ---------------- convert kernels ----------------
__global__ void cvt_bf16(const float* __restrict__ in, short* __restrict__ out, int n) {
    int i = (blockIdx.x * 256 + threadIdx.x) * 4;
    if (i >= n) return;
    float4 v = *(const float4*)(in + i);
    short4 o = make_short4(f2b(v.x), f2b(v.y), f2b(v.z), f2b(v.w));
    *(short4*)(out + i) = o;
}

// 4 weights f32 [1024][1024] -> Wt bf16 [N][K], dsts contiguous from Wt0
__global__ void cvt_t4(const float* __restrict__ W0, const float* __restrict__ W1,
                       const float* __restrict__ W2, const float* __restrict__ W3,
                       short* __restrict__ Wt0) {
    __shared__ short tile[32][33];
    const float* Ws[4] = {W0, W1, W2, W3};
    const float* W = Ws[blockIdx.z];
    short* Wt = Wt0 + (size_t)blockIdx.z * 1024 * 1024;
    const int K = 1024, N = 1024;
    int n0 = blockIdx.x * 32, k0 = blockIdx.y * 32;
    int tx = threadIdx.x, ty = threadIdx.y; // (32,8)
#pragma unroll
    for (int i = 0; i < 4; i++) {
        int r = ty + i * 8;
        tile[r][tx] = f2b(W[(size_t)(k0 + r) * N + n0 + tx]);
    }
    __syncthreads();
#pragma unroll
    for (int i = 0; i < 4; i++) {
        int r = ty + i * 8;
        Wt[(size_t)(n0 + r) * K + k0 + tx] = tile[tx][r];
    }
}

// ---------------- GEMM 256x256: 8-wave, counted-vmcnt pipeline, coalesced V^T ----------------
// KV projection only (M=16384, N=2048, K=1024). Grid (8,64): nx<4 -> K blocks (direct
// coalesced [m][1024] write); nx>=4 -> V blocks (LDS-transposed epilogue -> coalesced
// Vt[b][h][d][s] rows).
__global__ __launch_bounds__(512, 1) void gemm256(
    const short* __restrict__ A, const short* __restrict__ Bt,
    short* __restrict__ CK, short* __restrict__ CVt)
{
    __shared__ short lds[65536];   // As[2][16384] | Bs[2][16384]; reused as [256][256] T-buf
    const int tid = threadIdx.x;
    const int w = tid >> 6, L = tid & 63, quad = L >> 4, l16 = L & 15;
    const int wr = w >> 2, wcn = w & 3;   // 2x4 wave grid; per-wave output 128x64

    const int lin = blockIdx.y * gridDim.x + blockIdx.x;
    const int xcd = lin & 7, idx = lin >> 3;
    const int mPer = gridDim.y >> 3;      // 64/8 = 8
    const int my = xcd * mPer + idx / gridDim.x;
    const int nx = idx % gridDim.x;
    const int n0 = nx * 256, m0 = my * 256;

    const int K = 1024;
    const int srow_in = L >> 3;                    // 0..7 within 8-row chunk
    const int sgcol   = ((L & 7) ^ srow_in) * 8;   // pre-swizzled global col (shorts)

    // 64 chunks of 8 rows x 64 cols: waves 0-3 stage A (chunks 0-31), 4-7 stage B.
    auto STAGE_ALL = [&](int buf, int kt) {
        const int k0 = kt * 64;
#pragma unroll
        for (int j = 0; j < 8; j++) {
            int c = w * 8 + j;
            if (c < 32) {
                int row = c * 8 + srow_in;
                GLDS(A + (size_t)(m0 + row) * K + k0 + sgcol, &lds[buf * 16384 + c * 512]);
            } else {
                int row = (c - 32) * 8 + srow_in;
                GLDS(Bt + (size_t)(n0 + row) * K + k0 + sgcol, &lds[32768 + buf * 16384 + (c - 32) * 512]);
            }
        }
    };

    f32x4 acc[2][4][4];
#pragma unroll
    for (int mh = 0; mh < 2; mh++)
#pragma unroll
        for (int mi = 0; mi < 4; mi++)
#pragma unroll
            for (int ni = 0; ni < 4; ni++) acc[mh][mi][ni] = (f32x4){0.f, 0.f, 0.f, 0.f};

    STAGE_ALL(0, 0);   // prologue; drained by first TOPSYNC

    for (int t = 0; t < 16; t++) {
        const int cur = t & 1;
        if (t < 15) {
            STAGE_ALL(cur ^ 1, t + 1);
            TOPSYNC_V(8);          // drain prev tile's 8, keep the 8 just issued flying
        } else {
            TOPSYNC_V(0);          // last tile: drain fully
        }
#pragma unroll
        for (int ks = 0; ks < 2; ks++) {
            const int swz = (((ks * 4) + quad) ^ (l16 & 7)) << 3;
            short8 bf[4];
#pragma unroll
            for (int ni = 0; ni < 4; ni++)
                bf[ni] = *(const short8*)&lds[32768 + cur * 16384 + (wcn * 64 + ni * 16 + l16) * 64 + swz];
#pragma unroll
            for (int mh = 0; mh < 2; mh++) {
                short8 af[4];
#pragma unroll
                for (int mi = 0; mi < 4; mi++)
                    af[mi] = *(const short8*)&lds[cur * 16384 + (wr * 128 + mh * 64 + mi * 16 + l16) * 64 + swz];
                __builtin_amdgcn_s_setprio(1);
#pragma unroll
                for (int mi = 0; mi < 4; mi++)
#pragma unroll
                    for (int ni = 0; ni < 4; ni++)
                        acc[mh][mi][ni] = __builtin_amdgcn_mfma_f32_16x16x32_bf16(af[mi], bf[ni], acc[mh][mi][ni], 0, 0, 0);
                __builtin_amdgcn_s_setprio(0);
            }
        }
        ENDSYNC();   // all reads of buf[cur] done; next iter may overwrite it
    }

    if (n0 < 1024) {
        // K half: direct coalesced [m][1024] bf16 write
#pragma unroll
        for (int mh = 0; mh < 2; mh++)
#pragma unroll
            for (int ni = 0; ni < 4; ni++) {
                int n = n0 + wcn * 64 + ni * 16 + l16;
#pragma unroll
                for (int mi = 0; mi < 4; mi++)
#pragma unroll
                    for (int r = 0; r < 4; r++) {
                        int m = m0 + wr * 128 + mh * 64 + mi * 16 + quad * 4 + r;
                        CK[(size_t)m * 1024 + n] = f2b(acc[mh][mi][ni][r]);
                    }
            }
    } else {
        // V half: transpose 256x256 through LDS (free after last ENDSYNC), then
        // write Vt[b][h][d][s] rows fully coalesced.
#pragma unroll
        for (int mh = 0; mh < 2; mh++)
#pragma unroll
            for (int mi = 0; mi < 4; mi++) {
                const int g = wr * 32 + mh * 16 + mi * 4 + quad;   // m-granule 0..63
#pragma unroll
                for (int ni = 0; ni < 4; ni++) {
                    int n = wcn * 64 + ni * 16 + l16;              // local n 0..255
                    short4v v;
#pragma unroll
                    for (int r = 0; r < 4; r++) v[r] = f2b(acc[mh][mi][ni][r]);
                    *(short4v*)&lds[n * 256 + ((g ^ (n & 15)) << 2)] = v;
                }
            }
        __syncthreads();
        const int hb = (n0 - 1024) >> 6;
        const int bb = m0 >> 11, sb = m0 & 2047;
#pragma unroll
        for (int i = 0; i < 16; i++) {
            int row = w * 32 + i * 2 + (L >> 5);      // local n
            int cg  = (L & 31) * 2;                   // granule pair (m-cols)
            int sw  = row & 15;
            short4v a = *(const short4v*)&lds[row * 256 + ((cg ^ sw) << 2)];
            short4v c2 = *(const short4v*)&lds[row * 256 + (((cg + 1) ^ sw) << 2)];
            short8 o;
            o[0] = a[0]; o[1] = a[1]; o[2] = a[2]; o[3] = a[3];
            o[4] = c2[0]; o[5] = c2[1]; o[6] = c2[2]; o[7] = c2[3];
            int h = hb + (row >> 6), d = row & 63;
            *(short8*)&CVt[(((size_t)bb * 16 + h) * 64 + d) * 2048 + sb + (L & 31) * 8] = o;
        }
    }
}

// ---------------- GEMM: 128m x 128n tile, BK=64, counted-vmcnt 2-phase ----------------
// Q/O projections. mode 0: bf16 [m][n]; mode 1: f32 [m][n]
__global__ __launch_bounds__(256) void gemm128(
    const short* __restrict__ A, const short* __restrict__ Bt,
    const float* __restrict__ bias, void* __restrict__ Cout,
    int M, int mode)
{
    __shared__ short As[2][128 * 64];
    __shared__ short Bs[2][128 * 64];
    const int tid = threadIdx.x;
    const int w = tid >> 6, L = tid & 63, quad = L >> 4, l16 = L & 15;
    const int wr = w >> 1, wc = w & 1;   // 2x2 wave grid, each wave owns 64x64

    const int lin = blockIdx.y * gridDim.x + blockIdx.x;
    const int xcd = lin & 7, idx = lin >> 3;
    const int mPer = gridDim.y >> 3;
    const int my = xcd * mPer + idx / gridDim.x;
    const int nx = idx % gridDim.x;
    const int n0 = nx * 128, m0 = my * 128;

    const int K = 1024;
    const int srow_in = L >> 3;                        // 0..7 within chunk
    const int sgcol   = ((L & 7) ^ (srow_in & 7)) * 8; // swizzled global col (shorts)

    auto STAGE = [&](int buf, int k0) {
#pragma unroll
        for (int j = 0; j < 8; j++) {
            int c = w * 8 + j;
            if (c < 16) {
                int row = c * 8 + srow_in;
                GLDS(A + (size_t)(m0 + row) * K + k0 + sgcol, &As[buf][c * 512]);
            } else {
                int row = (c - 16) * 8 + srow_in;
                GLDS(Bt + (size_t)(n0 + row) * K + k0 + sgcol, &Bs[buf][(c - 16) * 512]);
            }
        }
    };

    f32x4 acc[4][4];
#pragma unroll
    for (int mi = 0; mi < 4; mi++)
#pragma unroll
        for (int ni = 0; ni < 4; ni++) acc[mi][ni] = (f32x4){0.f, 0.f, 0.f, 0.f};

    STAGE(0, 0);   // prologue

    for (int t = 0; t < 16; t++) {
        const int cur = t & 1;
        if (t < 15) {
            STAGE(cur ^ 1, (t + 1) * 64);
            TOPSYNC_V(8);
        } else {
            TOPSYNC_V(0);
        }
#pragma unroll
        for (int kk = 0; kk < 64; kk += 32) {
            const int swz = (((kk >> 3) + quad) ^ (l16 & 7)) << 3;
            short8 af[4], bf[4];
#pragma unroll
            for (int mi = 0; mi < 4; mi++)
                af[mi] = *(const short8*)&As[cur][(wr * 64 + mi * 16 + l16) * 64 + swz];
#pragma unroll
            for (int ni = 0; ni < 4; ni++)
                bf[ni] = *(const short8*)&Bs[cur][(wc * 64 + ni * 16 + l16) * 64 + swz];
#pragma unroll
            for (int mi = 0; mi < 4; mi++)
#pragma unroll
                for (int ni = 0; ni < 4; ni++)
                    acc[mi][ni] = __builtin_amdgcn_mfma_f32_16x16x32_bf16(af[mi], bf[ni], acc[mi][ni], 0, 0, 0);
        }
        ENDSYNC();
    }

#pragma unroll
    for (int ni = 0; ni < 4; ni++) {
        int n = n0 + wc * 64 + ni * 16 + l16;
        float bv = bias ? bias[n] : 0.f;
#pragma unroll
        for (int mi = 0; mi < 4; mi++) {
#pragma unroll
            for (int r = 0; r < 4; r++) {
                int m = m0 + wr * 64 + mi * 16 + quad * 4 + r;
                float v = acc[mi][ni][r] + bv;
                if (mode == 1)      ((float*)Cout)[(size_t)m * 1024 + n] = v;
                else                ((short*)Cout)[(size_t)m * 1024 + n] = f2b(v);
            }
        }
    }
}

// ---------------- flash attention: t-tile=128, s-tile=64, 2 blocks/CU ----------------
// Occupancy-first redesign: LDS 58KB (Q-staging aliased onto Ps; s-tile 64 dbuf K/V)
// -> 2 blocks/CU so cross-block overlap hides the per-iter drain+barrier stalls.
__global__ __launch_bounds__(512, 4) void attn_flash(
    const short* __restrict__ Qb, const short* __restrict__ Kb, const short* __restrict__ Vtb,
    const int* __restrict__ mask, short* __restrict__ Cb, float* __restrict__ lse)
{
    __shared__ short QPs[128 * LSK];       // prologue: Q [128][64]; loop: Ps [128][LSK]
    __shared__ short Ks[2][64 * 64];       // dbuf K rows
    __shared__ short Vts[2][64 * 64];      // dbuf V^T [64 d][64 s]
    __shared__ int   negi[2048];           // whole-row mask, staged once in prologue
    const int tid = threadIdx.x;
    const int w = tid >> 6, L = tid & 63, quad = L >> 4, l16 = L & 15;
    const int t0 = blockIdx.x * 128, h = blockIdx.y, b = blockIdx.z;
    const int S = 2048, T = 512, H = 1024;
    const int trow = w * 16;
    const int srow = L >> 3;
    const int sg   = ((L & 7) ^ srow) * 8;

    auto STAGE_KV = [&](int buf, int s0) {   // 2 glds/thread: wave w stages 8-row chunk w
        GLDS(Kb + ((size_t)b * S + s0 + w * 8 + srow) * H + h * 64 + sg, &Ks[buf][w * 512]);
        GLDS(Vtb + (((size_t)b * 16 + h) * 64 + w * 8 + srow) * S + s0 + sg, &Vts[buf][w * 512]);
    };

    // prologue: Q tile [128][64] into QPs (stride 64) + mask row + first K/V tile
#pragma unroll
    for (int j = 0; j < 2; j++) {
        int row = w * 16 + j * 8 + srow;
        GLDS(Qb + ((size_t)b * T + t0 + row) * H + h * 64 + sg, &QPs[(w * 16 + j * 8) * 64]);
    }
#pragma unroll
    for (int r = 0; r < 4; r++)
        GLDS4(mask + (size_t)b * S + r * 512 + w * 64 + L, &negi[r * 512 + w * 64]);
    STAGE_KV(0, 0);
    __syncthreads();

    short8 aq[2];
#pragma unroll
    for (int kk = 0; kk < 2; kk++)
        aq[kk] = *(const short8*)&QPs[(trow + l16) * 64 + ((kk * 4 + quad) ^ (l16 & 7)) * 8];
    // Drain this wave's Q reads before crossing the next barrier: QPs becomes Ps after it.
    asm volatile("s_waitcnt lgkmcnt(0)" ::: "memory");

    f32x4 Oacc[4];
#pragma unroll
    for (int nt = 0; nt < 4; nt++) Oacc[nt] = (f32x4){0.f, 0.f, 0.f, 0.f};
    float lsum[4] = {0.f, 0.f, 0.f, 0.f};

    for (int it = 0; it < 32; it++) {
        const int cur = it & 1;
        if (it < 31) {
            STAGE_KV(cur ^ 1, (it + 1) * 64);
            TOPSYNC_V(2);
        } else {
            TOPSYNC_V(0);
        }
        // S = Q K^T for this 64-s tile
        f32x4 sacc[4];
#pragma unroll
        for (int nt = 0; nt < 4; nt++) sacc[nt] = (f32x4){0.f, 0.f, 0.f, 0.f};
#pragma unroll
        for (int kk = 0; kk < 2; kk++) {
#pragma unroll
            for (int nt = 0; nt < 4; nt++) {
                short8 bf = *(const short8*)&Ks[cur][(nt * 16 + l16) * 64 + ((kk * 4 + quad) ^ (l16 & 7)) * 8];
                sacc[nt] = __builtin_amdgcn_mfma_f32_16x16x32_bf16(aq[kk], bf, sacc[nt], 0, 0, 0);
            }
        }
        // p = exp(s/8 + neg); write Ps (wave-private rows)
#pragma unroll
        for (int nt = 0; nt < 4; nt++) {
            float ng = negi[it * 64 + nt * 16 + l16] ? 0.f : -1e20f;
#pragma unroll
            for (int r = 0; r < 4; r++) {
                float e = __expf(fmaf(sacc[nt][r], 0.125f, ng));
                lsum[r] += e;
                QPs[(trow + quad * 4 + r) * LSK + nt * 16 + l16] = f2b(e);
            }
        }
        // O += P V
#pragma unroll
        for (int kk = 0; kk < 2; kk++) {
            short8 af = *(const short8*)&QPs[(trow + l16) * LSK + kk * 32 + quad * 8];
#pragma unroll
            for (int nt = 0; nt < 4; nt++) {
                short8 bf = *(const short8*)&Vts[cur][(nt * 16 + l16) * 64 + ((kk * 4 + quad) ^ (l16 & 7)) * 8];
                Oacc[nt] = __builtin_amdgcn_mfma_f32_16x16x32_bf16(af, bf, Oacc[nt], 0, 0, 0);
            }
        }
        ENDSYNC();
    }
    // rowsum reduce across the 16 lanes of each quad-group
#pragma unroll
    for (int r = 0; r < 4; r++) {
#pragma unroll
        for (int off = 1; off < 16; off <<= 1)
            lsum[r] += __shfl_xor(lsum[r], off, 64);
    }
#pragma unroll
    for (int r = 0; r < 4; r++) {
        float inv = 1.0f / lsum[r];
        int t = t0 + trow + quad * 4 + r;
#pragma unroll
        for (int nt = 0; nt < 4; nt++) {
            int d = nt * 16 + l16;
            Cb[((size_t)b * T + t) * H + h * 64 + d] = f2b(Oacc[nt][r] * inv);
        }
        if (l16 == 0)
            lse[((size_t)b * 16 + h) * T + t] = __logf(lsum[r]);
    }
}

// ---------------- a_mean: out[b][t][s] = mean_h exp(qk/8 + neg - lse_h) ----------------
// tiles 128x128 (512 thr): Q redundancy x16, K x4.
__global__ __launch_bounds__(512) void attn_amean(
    const short* __restrict__ Qb, const short* __restrict__ Kb,
    const int* __restrict__ mask, const float* __restrict__ lse, float* __restrict__ outA)
{
    __shared__ short Qs[2][128 * 64];
    __shared__ short Ks[2][128 * 64];
    __shared__ float neg[128];
    __shared__ float lss[16 * 128];
    const int tid = threadIdx.x;
    const int w = tid >> 6, L = tid & 63, quad = L >> 4, l16 = L & 15;
    const int s0 = blockIdx.x * 128, t0 = blockIdx.y * 128, b = blockIdx.z;
    const int S = 2048, T = 512, H = 1024;
    const int srow = L >> 3;
    const int sg   = ((L & 7) ^ srow) * 8;

    auto STAGE_QK = [&](int buf, int h) {   // 4 glds/thread, uniform (8 waves x 2j x 8 rows = 128)
#pragma unroll
        for (int j = 0; j < 2; j++) {
            int row = w * 16 + j * 8 + srow;
            GLDS(Qb + ((size_t)b * T + t0 + row) * H + h * 64 + sg, &Qs[buf][(w * 16 + j * 8) * 64]);
            GLDS(Kb + ((size_t)b * S + s0 + row) * H + h * 64 + sg, &Ks[buf][(w * 16 + j * 8) * 64]);
        }
    };

    if (tid < 128) neg[tid] = mask[(size_t)b * S + s0 + tid] ? 0.f : -1e20f;
    for (int i = tid; i < 16 * 128; i += 512) {
        int hh = i >> 7, tt = i & 127;
        lss[i] = lse[((size_t)b * 16 + hh) * T + t0 + tt];
    }
    STAGE_QK(0, 0);
    __syncthreads();   // neg/lss settled, head-0 staged, vmcnt drained

    float am[8][4] = {};
    for (int h = 0; h < 16; h++) {
        const int cur = h & 1;
        if (h < 15) {
            STAGE_QK(cur ^ 1, h + 1);
            TOPSYNC_V(4);
        } else {
            TOPSYNC_V(0);
        }
        short8 aq[2];
#pragma unroll
        for (int kk = 0; kk < 2; kk++)
            aq[kk] = *(const short8*)&Qs[cur][(w * 16 + l16) * 64 + ((kk * 4 + quad) ^ (l16 & 7)) * 8];
        f32x4 sacc[8];
#pragma unroll
        for (int nt = 0; nt < 8; nt++) sacc[nt] = (f32x4){0.f, 0.f, 0.f, 0.f};
#pragma unroll
        for (int kk = 0; kk < 2; kk++) {
#pragma unroll
            for (int nt = 0; nt < 8; nt++) {
                short8 bf = *(const short8*)&Ks[cur][(nt * 16 + l16) * 64 + ((kk * 4 + quad) ^ (l16 & 7)) * 8];
                sacc[nt] = __builtin_amdgcn_mfma_f32_16x16x32_bf16(aq[kk], bf, sacc[nt], 0, 0, 0);
            }
        }
#pragma unroll
        for (int nt = 0; nt < 8; nt++) {
            float ng = neg[nt * 16 + l16];
#pragma unroll
            for (int r = 0; r < 4; r++) {
                int trow = w * 16 + quad * 4 + r;
                am[nt][r] += __expf(fmaf(sacc[nt][r], 0.125f, ng - lss[h * 128 + trow]));
            }
        }
        ENDSYNC();
    }
#pragma unroll
    for (int r = 0; r < 4; r++) {
        int t = t0 + w * 16 + quad * 4 + r;
#pragma unroll
        for (int nt = 0; nt < 8; nt++) {
            int s = s0 + nt * 16 + l16;
            outA[((size_t)b * T + t) * S + s] = am[nt][r] * 0.0625f;
        }
    }
}

// ---------------- launch ----------------
extern "C" void kernel_launch(void* const* d_in, const int* in_sizes, int n_in,
                              void* d_out, int out_size, void* d_ws, size_t ws_size,
                              hipStream_t stream) {
    const float* hiddens = (const float*)d_in[0];
    const float* query   = (const float*)d_in[1];
    const int*   mask    = (const int*)d_in[2];
    const float* W_q = (const float*)d_in[3];
    const float* b_q = (const float*)d_in[4];
    const float* W_k = (const float*)d_in[5];
    const float* W_v = (const float*)d_in[6];
    const float* W_o = (const float*)d_in[7];
    const float* b_o = (const float*)d_in[8];
    float* out = (float*)d_out;

    constexpr size_t N_H  = 8UL * 2048 * 1024;  // 16777216
    constexpr size_t N_QH = 8UL * 512 * 1024;   // 4194304
    constexpr size_t N_W  = 1024UL * 1024;      // 1048576
    char* ws = (char*)d_ws;
    short* Hb   = (short*)(ws);
    short* QHb  = (short*)(ws + N_H * 2);
    short* Wqt  = (short*)(ws + N_H * 2 + N_QH * 2);
    short* Wkt  = Wqt + N_W;
    short* Wvt  = Wkt + N_W;   // contiguous after Wkt: enables N=2048 dual GEMM
    short* Wot  = Wvt + N_W;
    short* Qb   = Wot + N_W;
    short* Kb   = Qb + N_QH;
    short* Vtb  = Kb + N_H;    // V stored transposed: [b][h][d][s]
    short* Cb   = Vtb + N_H;
    float* lseP = (float*)(Cb + N_QH);

    cvt_bf16<<<16384, 256, 0, stream>>>(hiddens, Hb, (int)N_H);
    cvt_bf16<<<4096, 256, 0, stream>>>(query, QHb, (int)N_QH);
    cvt_t4<<<dim3(32, 32, 4), dim3(32, 8), 0, stream>>>(W_q, W_k, W_v, W_o, Wqt);

    gemm128<<<dim3(8, 32), 256, 0, stream>>>(QHb, Wqt, b_q, Qb, 4096, 0);
    // fused K+V projection as one wide GEMM (N=2048), 256^2 counted-vmcnt pipeline
    gemm256<<<dim3(8, 64), 512, 0, stream>>>(Hb, Wkt, Kb, Vtb);

    attn_flash<<<dim3(4, 16, 8), 512, 0, stream>>>(Qb, Kb, Vtb, mask, Cb, lseP);

    gemm128<<<dim3(8, 32), 256, 0, stream>>>(Cb, Wot, b_o, out, 4096, 1);
    attn_amean<<<dim3(16, 4, 8), 512, 0, stream>>>(Qb, Kb, mask, lseP, out + N_QH);
}